// Round 2
// baseline (8994.905 us; speedup 1.0000x reference)
//
#include <hip/hip_runtime.h>
#include <hip/hip_bf16.h>

// Problem constants (PerformerSelfLayer): B=4, N=4096, D=1024, H=16, DH=64, M=256, DFF=4096
#define N_TOK   4096
#define DMODEL  1024
#define NHEADS  16
#define DH      64
#define MFEAT   256
#define DFF     4096
#define BATCH   4
#define ROWS    (BATCH * N_TOK)   // 16384
#define BHN     (BATCH * NHEADS)  // 64

#define NORMF      0.35355339059327373f  // 64^-0.25
#define HALF_NORM2 0.0625f               // 0.5 * norm^2
#define RATIO      0.0625f               // 256^-0.5
#define EPSK       1e-4f
#define LNEPS      1e-5f

__device__ __forceinline__ float ldA(const float* p) { return *p; }
__device__ __forceinline__ float ldA(const __hip_bfloat16* p) { return __bfloat162float(*p); }
__device__ __forceinline__ void stC(float* p, float v) { *p = v; }
__device__ __forceinline__ void stC(__hip_bfloat16* p, float v) { *p = __float2bfloat16(v); }

// order-preserving float->uint key for atomicMax; memset(0) is below any real key
__device__ __forceinline__ unsigned fkey(float f) {
    unsigned u = __float_as_uint(f);
    return (u & 0x80000000u) ? ~u : (u | 0x80000000u);
}
__device__ __forceinline__ float fdec(unsigned k) {
    return (k & 0x80000000u) ? __uint_as_float(k ^ 0x80000000u) : __uint_as_float(~k);
}

// ---------------- generic tiled GEMM: C[M,N] = A[M,K] * W[N,K]^T + bias, optional relu
template <typename AT, typename OT>
__global__ __launch_bounds__(256) void gemm_bias(
    const AT* __restrict__ A, const float* __restrict__ W,
    const float* __restrict__ bias, OT* __restrict__ C,
    int Nout, int K, int relu)
{
    __shared__ float As[16][68];   // [k][m]
    __shared__ float Ws[16][68];   // [k][n]
    const int t  = threadIdx.x;
    const int m0 = blockIdx.y * 64, n0 = blockIdx.x * 64;
    const int tm = t >> 4, tn = t & 15;
    const int lk = t & 15, lr = t >> 4;
    float acc[4][4] = {{0.f, 0.f, 0.f, 0.f}};
    for (int k0 = 0; k0 < K; k0 += 16) {
#pragma unroll
        for (int i = 0; i < 4; ++i) {
            int mm = lr + i * 16;
            As[lk][mm] = ldA(A + (size_t)(m0 + mm) * K + k0 + lk);
            Ws[lk][mm] = W[(size_t)(n0 + mm) * K + k0 + lk];
        }
        __syncthreads();
#pragma unroll
        for (int kk = 0; kk < 16; ++kk) {
            float av[4], bv[4];
#pragma unroll
            for (int i = 0; i < 4; ++i) av[i] = As[kk][tm * 4 + i];
#pragma unroll
            for (int j = 0; j < 4; ++j) bv[j] = Ws[kk][tn * 4 + j];
#pragma unroll
            for (int i = 0; i < 4; ++i)
#pragma unroll
                for (int j = 0; j < 4; ++j) acc[i][j] = fmaf(av[i], bv[j], acc[i][j]);
        }
        __syncthreads();
    }
#pragma unroll
    for (int i = 0; i < 4; ++i) {
        int m = m0 + tm * 4 + i;
#pragma unroll
        for (int j = 0; j < 4; ++j) {
            int n = n0 + tn * 4 + j;
            float v = acc[i][j] + bias[n];
            if (relu) v = fmaxf(v, 0.f);
            stC(C + (size_t)m * Nout + n, v);
        }
    }
}

// ---------------- per-(b,h) global max of norm*(k . proj^T); K is bf16
__global__ __launch_bounds__(256) void kstab_kernel(
    const __hip_bfloat16* __restrict__ Kmat, const float* __restrict__ proj,
    unsigned* __restrict__ kmax)
{
    __shared__ float pl[MFEAT][65];   // 66.6 KB
    __shared__ float krow[DH];
    __shared__ float red[256];
    const int t = threadIdx.x;
    for (int idx = t; idx < MFEAT * DH; idx += 256)
        pl[idx >> 6][idx & 63] = proj[idx];
    const int bh = blockIdx.y, b = bh >> 4, h = bh & 15;
    const int n0 = blockIdx.x * 128;
    const __hip_bfloat16* Kb = Kmat + ((size_t)b * N_TOK) * DMODEL + h * DH;
    float mx = -1e30f;
    __syncthreads();
    for (int r = 0; r < 128; ++r) {
        if (t < DH) krow[t] = __bfloat162float(Kb[(size_t)(n0 + r) * DMODEL + t]);
        __syncthreads();
        float dot = 0.f;
#pragma unroll
        for (int j = 0; j < DH; ++j) dot += krow[j] * pl[t][j];
        mx = fmaxf(mx, dot);
        __syncthreads();
    }
    red[t] = mx;
    __syncthreads();
    for (int s = 128; s > 0; s >>= 1) {
        if (t < s) red[t] = fmaxf(red[t], red[t + s]);
        __syncthreads();
    }
    if (t == 0) atomicMax(kmax + bh, fkey(red[0] * NORMF));
}

// ---------------- fused kp + ctx GEMM + ksum (KP never materialized)
// ctx[bh][m][d] = sum_n kp(n,m) * V[b][n][h*64+d];  ksum[bh][m] = sum_n kp(n,m)
__global__ __launch_bounds__(256) void ctxkp_kernel(
    const __hip_bfloat16* __restrict__ Kmat, const __hip_bfloat16* __restrict__ V,
    const float* __restrict__ proj, const unsigned* __restrict__ kmax,
    float* __restrict__ ctx, float* __restrict__ ksum)
{
    __shared__ float P[64][65];     // proj rows [m0, m0+64)
    __shared__ float Ks[16][65];
    __shared__ float Vs[16][65];
    __shared__ float KPs[16][65];
    __shared__ float diag[16];
    __shared__ float ksred[256];
    const int t = threadIdx.x;
    const int bh = blockIdx.y, b = bh >> 4, h = bh & 15;
    const int m0 = blockIdx.x * 64;
    for (int idx = t; idx < 64 * DH; idx += 256)
        P[idx >> 6][idx & 63] = proj[(size_t)(m0 + (idx >> 6)) * DH + (idx & 63)];
    const float stab = fdec(kmax[bh]);
    const __hip_bfloat16* Kb = Kmat + ((size_t)b * N_TOK) * DMODEL + h * DH;
    const __hip_bfloat16* Vb = V + ((size_t)b * N_TOK) * DMODEL + h * DH;
    const int mm = t & 63, rq = t >> 6;      // kp compute mapping
    const int tm = t >> 4, tn = t & 15;      // GEMM mapping
    float acc[4][4] = {{0.f, 0.f, 0.f, 0.f}};
    float ksacc = 0.f;
    __syncthreads();
    for (int n0 = 0; n0 < N_TOK; n0 += 16) {
#pragma unroll
        for (int i = 0; i < 4; ++i) {
            int idx = t + i * 256;
            int r = idx >> 6, c = idx & 63;
            Ks[r][c] = __bfloat162float(Kb[(size_t)(n0 + r) * DMODEL + c]);
            Vs[r][c] = __bfloat162float(Vb[(size_t)(n0 + r) * DMODEL + c]);
        }
        __syncthreads();
        if (t < 16) {
            float s = 0.f;
#pragma unroll
            for (int j = 0; j < DH; ++j) s += Ks[t][j] * Ks[t][j];
            diag[t] = s;
        }
        __syncthreads();
#pragma unroll
        for (int i = 0; i < 4; ++i) {
            int r = rq * 4 + i;
            float dot = 0.f;
#pragma unroll
            for (int j = 0; j < DH; ++j) dot += Ks[r][j] * P[mm][j];
            float val = RATIO * (expf(NORMF * dot - HALF_NORM2 * diag[r] - stab) + EPSK);
            KPs[r][mm] = val;
            ksacc += val;
        }
        __syncthreads();
#pragma unroll
        for (int r = 0; r < 16; ++r) {
            float av[4], bv[4];
#pragma unroll
            for (int i = 0; i < 4; ++i) av[i] = KPs[r][tm * 4 + i];
#pragma unroll
            for (int j = 0; j < 4; ++j) bv[j] = Vs[r][tn * 4 + j];
#pragma unroll
            for (int i = 0; i < 4; ++i)
#pragma unroll
                for (int j = 0; j < 4; ++j) acc[i][j] = fmaf(av[i], bv[j], acc[i][j]);
        }
        __syncthreads();
    }
    ksred[t] = ksacc;
    __syncthreads();
    if (t < 64)
        ksum[bh * MFEAT + m0 + t] = ksred[t] + ksred[t + 64] + ksred[t + 128] + ksred[t + 192];
    float* cb = ctx + (size_t)bh * MFEAT * DH;
#pragma unroll
    for (int i = 0; i < 4; ++i)
#pragma unroll
        for (int j = 0; j < 4; ++j)
            cb[(size_t)(m0 + tm * 4 + i) * DH + tn * 4 + j] = acc[i][j];
}

// ---------------- fused q-features + attention output (head-merged layout)
__global__ __launch_bounds__(256) void qout_kernel(
    const float* __restrict__ Q, const float* __restrict__ proj,
    const float* __restrict__ ctx, const float* __restrict__ ksum,
    float* __restrict__ OUT)
{
    __shared__ __hip_bfloat16 pl[MFEAT][66];
    __shared__ float qrow[DH];
    __shared__ float red[256];
    __shared__ float qp[MFEAT];
    const int t = threadIdx.x;
    for (int idx = t; idx < MFEAT * DH; idx += 256)
        pl[idx >> 6][idx & 63] = __float2bfloat16(proj[idx]);
    const int bh = blockIdx.y, b = bh >> 4, h = bh & 15;
    const int n0 = blockIdx.x * 16;
    const float* Qb = Q + ((size_t)b * N_TOK) * DMODEL + h * DH;
    const float* ctxb = ctx + (size_t)bh * MFEAT * DH;
    const float ks = ksum[bh * MFEAT + t];
    const int d = t & 63, qtr = t >> 6;
    __syncthreads();
    for (int r = 0; r < 16; ++r) {
        const int n = n0 + r;
        if (t < DH) qrow[t] = Qb[(size_t)n * DMODEL + t];
        __syncthreads();
        float dot = 0.f, ss = 0.f;
#pragma unroll
        for (int j = 0; j < DH; ++j) {
            float qv = qrow[j];
            dot += qv * __bfloat162float(pl[t][j]);
            ss  += qv * qv;
        }
        float xq = NORMF * dot;
        red[t] = xq;
        __syncthreads();
        for (int s = 128; s > 0; s >>= 1) {
            if (t < s) red[t] = fmaxf(red[t], red[t + s]);
            __syncthreads();
        }
        float stab = red[0];
        __syncthreads();
        float p = RATIO * (expf(xq - HALF_NORM2 * ss - stab) + EPSK);
        qp[t] = p;
        red[t] = p * ks;
        __syncthreads();
        for (int s = 128; s > 0; s >>= 1) {
            if (t < s) red[t] += red[t + s];
            __syncthreads();
        }
        float denom = red[0];
        __syncthreads();
        const float* cb = ctxb + (size_t)qtr * 64 * DH + d;
        const float* qpb = qp + qtr * 64;
        float part = 0.f;
#pragma unroll 8
        for (int i = 0; i < 64; ++i) part += qpb[i] * cb[(size_t)i * DH];
        red[t] = part;
        __syncthreads();
        if (t < DH) {
            float o = red[t] + red[t + 64] + red[t + 128] + red[t + 192];
            OUT[((size_t)(b * N_TOK + n)) * DMODEL + h * DH + t] = o / denom;
        }
        __syncthreads();
    }
}

// ---------------- LayerNorm(out = LN(A + Badd) * g + b), row-per-block, D=1024
__global__ __launch_bounds__(256) void ln_kernel(
    const float* __restrict__ A, const float* __restrict__ Badd,
    const float* __restrict__ g, const float* __restrict__ bb,
    float* __restrict__ out)
{
    __shared__ float red[256];
    const int row = blockIdx.x, t = threadIdx.x;
    const float* a = A + (size_t)row * DMODEL;
    const float* c = Badd + (size_t)row * DMODEL;
    float v[4];
    float s = 0.f;
#pragma unroll
    for (int i = 0; i < 4; ++i) {
        int col = t + i * 256;
        v[i] = a[col] + c[col];
        s += v[i];
    }
    red[t] = s;
    __syncthreads();
    for (int st = 128; st > 0; st >>= 1) { if (t < st) red[t] += red[t + st]; __syncthreads(); }
    float mu = red[0] * (1.f / DMODEL);
    __syncthreads();
    float sq = 0.f;
#pragma unroll
    for (int i = 0; i < 4; ++i) { float dlt = v[i] - mu; sq += dlt * dlt; }
    red[t] = sq;
    __syncthreads();
    for (int st = 128; st > 0; st >>= 1) { if (t < st) red[t] += red[t + st]; __syncthreads(); }
    float rstd = rsqrtf(red[0] * (1.f / DMODEL) + LNEPS);
    float* o = out + (size_t)row * DMODEL;
#pragma unroll
    for (int i = 0; i < 4; ++i) {
        int col = t + i * 256;
        o[col] = (v[i] - mu) * rstd * g[col] + bb[col];
    }
}

extern "C" void kernel_launch(void* const* d_in, const int* in_sizes, int n_in,
                              void* d_out, int out_size, void* d_ws, size_t ws_size,
                              hipStream_t stream)
{
    const float* video = (const float*)d_in[0];
    const float* Wq = (const float*)d_in[1];
    const float* bq = (const float*)d_in[2];
    const float* Wk = (const float*)d_in[3];
    const float* bk = (const float*)d_in[4];
    const float* Wv = (const float*)d_in[5];
    const float* bv = (const float*)d_in[6];
    const float* Wo = (const float*)d_in[7];
    const float* bo = (const float*)d_in[8];
    const float* proj = (const float*)d_in[9];
    const float* W1 = (const float*)d_in[10];
    const float* b1 = (const float*)d_in[11];
    const float* W2 = (const float*)d_in[12];
    const float* b2 = (const float*)d_in[13];
    const float* g2 = (const float*)d_in[14];
    const float* be2 = (const float*)d_in[15];
    const float* g3 = (const float*)d_in[16];
    const float* be3 = (const float*)d_in[17];

    // workspace map — peak use is exactly 128 MB:
    //   phase A: [0,32M) K bf16 | [32M,64M) V bf16 | [64M,68M) ctx | [68M,+64K) ksum | +256B kmax
    //   phase B: [0,64M) attn-out fp32 (K,V dead) | [64M,128M) Y fp32 (ctx/ksum dead)
    //   phase C: [0,64M) FFN hidden bf16 (8192-row half) | [64M,128M) FFN-out fp32
    //   Q and X(post-LN1) live in d_out.
    char* ws = (char*)d_ws;
    __hip_bfloat16* Kbuf = (__hip_bfloat16*)(ws + 0);
    __hip_bfloat16* Vbuf = (__hip_bfloat16*)(ws + 33554432ull);
    float* ctxbuf = (float*)(ws + 67108864ull);
    float* ksum   = (float*)(ws + 71303168ull);
    unsigned* kmax = (unsigned*)(ws + 71368704ull);
    float* OUTbuf = (float*)(ws + 0);
    __hip_bfloat16* Hbuf = (__hip_bfloat16*)(ws + 0);
    float* Ybuf = (float*)(ws + 67108864ull);
    float* Fbuf = (float*)(ws + 67108864ull);
    float* Qbuf = (float*)d_out;   // Q, then X(post-LN1)
    float* Xbuf = (float*)d_out;

    dim3 blk(256);
    dim3 gD(DMODEL / 64, ROWS / 64);   // (16,256)

    gemm_bias<float, float><<<gD, blk, 0, stream>>>(video, Wq, bq, Qbuf, DMODEL, DMODEL, 0);
    gemm_bias<float, __hip_bfloat16><<<gD, blk, 0, stream>>>(video, Wk, bk, Kbuf, DMODEL, DMODEL, 0);
    gemm_bias<float, __hip_bfloat16><<<gD, blk, 0, stream>>>(video, Wv, bv, Vbuf, DMODEL, DMODEL, 0);

    hipMemsetAsync(ws + 71368704ull, 0, 256, stream);  // kmax = key(-inf)

    kstab_kernel<<<dim3(N_TOK / 128, BHN), blk, 0, stream>>>(Kbuf, proj, kmax);
    ctxkp_kernel<<<dim3(MFEAT / 64, BHN), blk, 0, stream>>>(Kbuf, Vbuf, proj, kmax, ctxbuf, ksum);
    qout_kernel<<<dim3(N_TOK / 16, BHN), blk, 0, stream>>>(Qbuf, proj, ctxbuf, ksum, OUTbuf);

    gemm_bias<float, float><<<gD, blk, 0, stream>>>(OUTbuf, Wo, bo, Ybuf, DMODEL, DMODEL, 0);
    ln_kernel<<<dim3(ROWS), blk, 0, stream>>>(video, Ybuf, g2, be2, Xbuf);

    // FFN in two 8192-row halves, hidden (bf16) reuses [0,64M)
    for (int half = 0; half < 2; ++half) {
        const size_t r0 = (size_t)half * 8192;
        gemm_bias<float, __hip_bfloat16><<<dim3(DFF / 64, 8192 / 64), blk, 0, stream>>>(
            Xbuf + r0 * DMODEL, W1, b1, Hbuf, DFF, DMODEL, 1);
        gemm_bias<__hip_bfloat16, float><<<dim3(DMODEL / 64, 8192 / 64), blk, 0, stream>>>(
            Hbuf, W2, b2, Fbuf + r0 * DMODEL, DMODEL, DFF, 0);
    }
    ln_kernel<<<dim3(ROWS), blk, 0, stream>>>(Xbuf, Fbuf, g3, be3, (float*)d_out);
}

// Round 4
// 3247.512 us; speedup vs baseline: 2.7698x; 2.7698x over previous
//
#include <hip/hip_runtime.h>
#include <hip/hip_bf16.h>

// PerformerSelfLayer: B=4, N=4096, D=1024, H=16, DH=64, M=256, DFF=4096
#define N_TOK   4096
#define DMODEL  1024
#define NHEADS  16
#define DH      64
#define MFEAT   256
#define DFF     4096
#define BATCH   4
#define ROWS    (BATCH * N_TOK)   // 16384
#define BHN     (BATCH * NHEADS)  // 64

#define NORMF      0.35355339059327373f  // 64^-0.25
#define HALF_NORM2 0.0625f               // 0.5 * norm^2
#define RATIO      0.0625f               // 256^-0.5
#define EPSK       1e-4f
#define LNEPS      1e-5f

typedef unsigned short ushort_t;
using bfrag = __attribute__((ext_vector_type(8))) short;   // 8 bf16 (4 VGPRs)
using facc  = __attribute__((ext_vector_type(4))) float;   // 4 fp32 acc

__device__ __forceinline__ float b2f(ushort_t u) {
    return __bfloat162float(__builtin_bit_cast(__hip_bfloat16, u));
}
__device__ __forceinline__ ushort_t f2b(float f) {
    return __builtin_bit_cast(ushort_t, __float2bfloat16(f));
}
__device__ __forceinline__ void stC(float* p, float v) { *p = v; }
__device__ __forceinline__ void stC(ushort_t* p, float v) { *p = f2b(v); }

// order-preserving float->uint key for atomicMax; memset(0) is below any real key
__device__ __forceinline__ unsigned fkey(float f) {
    unsigned u = __float_as_uint(f);
    return (u & 0x80000000u) ? ~u : (u | 0x80000000u);
}
__device__ __forceinline__ float fdec(unsigned k) {
    return (k & 0x80000000u) ? __uint_as_float(k ^ 0x80000000u) : __uint_as_float(~k);
}

// ---------------- fp32 -> bf16 conversion (vectorized)
__global__ __launch_bounds__(256) void cvt_bf16(const float* __restrict__ s,
                                                ushort_t* __restrict__ d, int n4) {
    int i = blockIdx.x * 256 + threadIdx.x;
    if (i >= n4) return;
    float4 v = ((const float4*)s)[i];
    ushort_t o0 = f2b(v.x), o1 = f2b(v.y), o2 = f2b(v.z), o3 = f2b(v.w);
    ((ushort4*)d)[i] = make_ushort4(o0, o1, o2, o3);
}

// ---------------- bf16 MFMA GEMM: C[M,N] = A[M,K] (bf16) * W[N,K]^T (bf16) + bias
// 128 x (FJ*32) tile, 4 waves in 2x2, each wave 4xFJ tiles of 16x16x32.
template <int FJ, typename OT>
__global__ __launch_bounds__(256) void gemm_mfma(
    const ushort_t* __restrict__ A, const ushort_t* __restrict__ W,
    const float* __restrict__ bias, OT* __restrict__ C,
    int Nout, int K, int relu)
{
    constexpr int BN = FJ * 32;
    __shared__ short As[128][40];   // stride 40 shorts = 80B: 16B-aligned, conflict-free frags
    __shared__ short Ws[BN][40];
    const int t = threadIdx.x;
    const int m0 = blockIdx.y * 128, n0 = blockIdx.x * BN;
    const int lane = t & 63, wave = t >> 6;
    const int wr = (wave >> 1) * 64, wc = (wave & 1) * (FJ * 16);
    const int lm = lane & 15, kq = (lane >> 4) * 8;
    facc acc[4][FJ];
#pragma unroll
    for (int i = 0; i < 4; ++i)
#pragma unroll
        for (int j = 0; j < FJ; ++j) acc[i][j] = (facc){0.f, 0.f, 0.f, 0.f};

    for (int k0 = 0; k0 < K; k0 += 32) {
#pragma unroll
        for (int it = 0; it < 2; ++it) {              // A tile: 128x32 = 512 chunks of 8
            int ch = t + it * 256;
            int row = ch >> 2, c8 = (ch & 3) * 8;
            *(uint4*)&As[row][c8] = *(const uint4*)(A + (size_t)(m0 + row) * K + k0 + c8);
        }
#pragma unroll
        for (int it = 0; it < BN / 64; ++it) {        // W tile: BN x 32
            int ch = t + it * 256;
            int row = ch >> 2, c8 = (ch & 3) * 8;
            *(uint4*)&Ws[row][c8] = *(const uint4*)(W + (size_t)(n0 + row) * K + k0 + c8);
        }
        __syncthreads();
        bfrag af[4], bf[FJ];
#pragma unroll
        for (int i = 0; i < 4; ++i) af[i] = *(bfrag*)&As[wr + i * 16 + lm][kq];
#pragma unroll
        for (int j = 0; j < FJ; ++j) bf[j] = *(bfrag*)&Ws[wc + j * 16 + lm][kq];
#pragma unroll
        for (int i = 0; i < 4; ++i)
#pragma unroll
            for (int j = 0; j < FJ; ++j)
                acc[i][j] = __builtin_amdgcn_mfma_f32_16x16x32_bf16(af[i], bf[j], acc[i][j], 0, 0, 0);
        __syncthreads();
    }
    const int rq = (lane >> 4) * 4;   // C/D: col=lane&15, row=quad*4+reg
#pragma unroll
    for (int i = 0; i < 4; ++i)
#pragma unroll
        for (int j = 0; j < FJ; ++j) {
            int col = n0 + wc + j * 16 + lm;
            float bc = bias[col];
#pragma unroll
            for (int r = 0; r < 4; ++r) {
                int row = m0 + wr + i * 16 + rq + r;
                float v = acc[i][j][r] + bc;
                if (relu) v = fmaxf(v, 0.f);
                stC(C + (size_t)row * Nout + col, v);
            }
        }
}

// ---------------- per-(b,h) global max of norm*(k . proj^T); K is bf16
__global__ __launch_bounds__(256) void kstab_kernel(
    const ushort_t* __restrict__ Kmat, const float* __restrict__ proj,
    unsigned* __restrict__ kmax)
{
    __shared__ float pl[MFEAT][65];
    __shared__ float krow[DH];
    __shared__ float red[256];
    const int t = threadIdx.x;
    for (int idx = t; idx < MFEAT * DH; idx += 256)
        pl[idx >> 6][idx & 63] = proj[idx];
    const int bh = blockIdx.y, b = bh >> 4, h = bh & 15;
    const int n0 = blockIdx.x * 128;
    const ushort_t* Kb = Kmat + ((size_t)b * N_TOK) * DMODEL + h * DH;
    float mx = -1e30f;
    __syncthreads();
    for (int r = 0; r < 128; ++r) {
        if (t < DH) krow[t] = b2f(Kb[(size_t)(n0 + r) * DMODEL + t]);
        __syncthreads();
        float dot = 0.f;
#pragma unroll
        for (int j = 0; j < DH; ++j) dot += krow[j] * pl[t][j];
        mx = fmaxf(mx, dot);
        __syncthreads();
    }
    red[t] = mx;
    __syncthreads();
    for (int s = 128; s > 0; s >>= 1) {
        if (t < s) red[t] = fmaxf(red[t], red[t + s]);
        __syncthreads();
    }
    if (t == 0) atomicMax(kmax + bh, fkey(red[0] * NORMF));
}

// ---------------- fused kp + ctx + ksum, N split 8 ways (blockIdx.z), atomic accumulate
__global__ __launch_bounds__(256) void ctxkp_kernel(
    const ushort_t* __restrict__ Kmat, const ushort_t* __restrict__ V,
    const float* __restrict__ proj, const unsigned* __restrict__ kmax,
    float* __restrict__ ctx, float* __restrict__ ksum)
{
    __shared__ float P[64][65];
    __shared__ float Ks[16][65];
    __shared__ float Vs[16][65];
    __shared__ float KPs[16][65];
    __shared__ float diag[16];
    __shared__ float ksred[256];
    const int t = threadIdx.x;
    const int bh = blockIdx.y, b = bh >> 4, h = bh & 15;
    const int m0 = blockIdx.x * 64;
    const int nbase = blockIdx.z * (N_TOK / 8);
    for (int idx = t; idx < 64 * DH; idx += 256)
        P[idx >> 6][idx & 63] = proj[(size_t)(m0 + (idx >> 6)) * DH + (idx & 63)];
    const float stab = fdec(kmax[bh]);
    const ushort_t* Kb = Kmat + ((size_t)b * N_TOK) * DMODEL + h * DH;
    const ushort_t* Vb = V + ((size_t)b * N_TOK) * DMODEL + h * DH;
    const int mm = t & 63, rq = t >> 6;
    const int tm = t >> 4, tn = t & 15;
    float acc[4][4] = {{0.f, 0.f, 0.f, 0.f}};
    float ksacc = 0.f;
    __syncthreads();
    for (int n0 = nbase; n0 < nbase + N_TOK / 8; n0 += 16) {
#pragma unroll
        for (int i = 0; i < 4; ++i) {
            int idx = t + i * 256;
            int r = idx >> 6, c = idx & 63;
            Ks[r][c] = b2f(Kb[(size_t)(n0 + r) * DMODEL + c]);
            Vs[r][c] = b2f(Vb[(size_t)(n0 + r) * DMODEL + c]);
        }
        __syncthreads();
        if (t < 16) {
            float s = 0.f;
#pragma unroll
            for (int j = 0; j < DH; ++j) s += Ks[t][j] * Ks[t][j];
            diag[t] = s;
        }
        __syncthreads();
#pragma unroll
        for (int i = 0; i < 4; ++i) {
            int r = rq * 4 + i;
            float dot = 0.f;
#pragma unroll
            for (int j = 0; j < DH; ++j) dot += Ks[r][j] * P[mm][j];
            float val = RATIO * (expf(NORMF * dot - HALF_NORM2 * diag[r] - stab) + EPSK);
            KPs[r][mm] = val;
            ksacc += val;
        }
        __syncthreads();
#pragma unroll
        for (int r = 0; r < 16; ++r) {
            float av[4], bv[4];
#pragma unroll
            for (int i = 0; i < 4; ++i) av[i] = KPs[r][tm * 4 + i];
#pragma unroll
            for (int j = 0; j < 4; ++j) bv[j] = Vs[r][tn * 4 + j];
#pragma unroll
            for (int i = 0; i < 4; ++i)
#pragma unroll
                for (int j = 0; j < 4; ++j) acc[i][j] = fmaf(av[i], bv[j], acc[i][j]);
        }
        __syncthreads();
    }
    ksred[t] = ksacc;
    __syncthreads();
    if (t < 64)
        atomicAdd(&ksum[bh * MFEAT + m0 + t],
                  ksred[t] + ksred[t + 64] + ksred[t + 128] + ksred[t + 192]);
    float* cb = ctx + (size_t)bh * MFEAT * DH;
#pragma unroll
    for (int i = 0; i < 4; ++i)
#pragma unroll
        for (int j = 0; j < 4; ++j)
            atomicAdd(&cb[(size_t)(m0 + tm * 4 + i) * DH + tn * 4 + j], acc[i][j]);
}

// ---------------- fused q-features + attention output (bf16 out, head-merged)
__global__ __launch_bounds__(256) void qout_kernel(
    const float* __restrict__ Q, const float* __restrict__ proj,
    const float* __restrict__ ctx, const float* __restrict__ ksum,
    ushort_t* __restrict__ OUT)
{
    __shared__ ushort_t pl[MFEAT][66];
    __shared__ float qrow[DH];
    __shared__ float red[256];
    __shared__ float qp[MFEAT];
    const int t = threadIdx.x;
    for (int idx = t; idx < MFEAT * DH; idx += 256)
        pl[idx >> 6][idx & 63] = f2b(proj[idx]);
    const int bh = blockIdx.y, b = bh >> 4, h = bh & 15;
    const int n0 = blockIdx.x * 16;
    const float* Qb = Q + ((size_t)b * N_TOK) * DMODEL + h * DH;
    const float* ctxb = ctx + (size_t)bh * MFEAT * DH;
    const float ks = ksum[bh * MFEAT + t];
    const int d = t & 63, qtr = t >> 6;
    __syncthreads();
    for (int r = 0; r < 16; ++r) {
        const int n = n0 + r;
        if (t < DH) qrow[t] = Qb[(size_t)n * DMODEL + t];
        __syncthreads();
        float dot = 0.f, ss = 0.f;
#pragma unroll
        for (int j = 0; j < DH; ++j) {
            float qv = qrow[j];
            dot += qv * b2f(pl[t][j]);
            ss  += qv * qv;
        }
        float xq = NORMF * dot;
        red[t] = xq;
        __syncthreads();
        for (int s = 128; s > 0; s >>= 1) {
            if (t < s) red[t] = fmaxf(red[t], red[t + s]);
            __syncthreads();
        }
        float stab = red[0];
        __syncthreads();
        float p = RATIO * (expf(xq - HALF_NORM2 * ss - stab) + EPSK);
        qp[t] = p;
        red[t] = p * ks;
        __syncthreads();
        for (int s = 128; s > 0; s >>= 1) {
            if (t < s) red[t] += red[t + s];
            __syncthreads();
        }
        float denom = red[0];
        __syncthreads();
        const float* cb = ctxb + (size_t)qtr * 64 * DH + d;
        const float* qpb = qp + qtr * 64;
        float part = 0.f;
#pragma unroll 8
        for (int i = 0; i < 64; ++i) part += qpb[i] * cb[(size_t)i * DH];
        red[t] = part;
        __syncthreads();
        if (t < DH) {
            float o = red[t] + red[t + 64] + red[t + 128] + red[t + 192];
            OUT[((size_t)(b * N_TOK + n)) * DMODEL + h * DH + t] = f2b(o / denom);
        }
        __syncthreads();
    }
}

// ---------------- LayerNorm: out = LN(A + Badd)*g + b; optional bf16 copy of out
__global__ __launch_bounds__(256) void ln_kernel(
    const float* __restrict__ A, const void* __restrict__ Badd, int badd_bf16,
    const float* __restrict__ g, const float* __restrict__ bb,
    float* __restrict__ out, ushort_t* __restrict__ out_bf)
{
    __shared__ float red[256];
    const int row = blockIdx.x, t = threadIdx.x;
    const float* a = A + (size_t)row * DMODEL;
    float v[4];
    float s = 0.f;
#pragma unroll
    for (int i = 0; i < 4; ++i) {
        int col = t + i * 256;
        float add = badd_bf16 ? b2f(((const ushort_t*)Badd)[(size_t)row * DMODEL + col])
                              : ((const float*)Badd)[(size_t)row * DMODEL + col];
        v[i] = a[col] + add;
        s += v[i];
    }
    red[t] = s;
    __syncthreads();
    for (int st = 128; st > 0; st >>= 1) { if (t < st) red[t] += red[t + st]; __syncthreads(); }
    float mu = red[0] * (1.f / DMODEL);
    __syncthreads();
    float sq = 0.f;
#pragma unroll
    for (int i = 0; i < 4; ++i) { float dlt = v[i] - mu; sq += dlt * dlt; }
    red[t] = sq;
    __syncthreads();
    for (int st = 128; st > 0; st >>= 1) { if (t < st) red[t] += red[t + st]; __syncthreads(); }
    float rstd = rsqrtf(red[0] * (1.f / DMODEL) + LNEPS);
    float* o = out + (size_t)row * DMODEL;
#pragma unroll
    for (int i = 0; i < 4; ++i) {
        int col = t + i * 256;
        float val = (v[i] - mu) * rstd * g[col] + bb[col];
        o[col] = val;
        if (out_bf) out_bf[(size_t)row * DMODEL + col] = f2b(val);
    }
}

extern "C" void kernel_launch(void* const* d_in, const int* in_sizes, int n_in,
                              void* d_out, int out_size, void* d_ws, size_t ws_size,
                              hipStream_t stream)
{
    const float* video = (const float*)d_in[0];
    const float* Wq = (const float*)d_in[1];
    const float* bq = (const float*)d_in[2];
    const float* Wk = (const float*)d_in[3];
    const float* bk = (const float*)d_in[4];
    const float* Wv = (const float*)d_in[5];
    const float* bv = (const float*)d_in[6];
    const float* Wo = (const float*)d_in[7];
    const float* bo = (const float*)d_in[8];
    const float* proj = (const float*)d_in[9];
    const float* W1 = (const float*)d_in[10];
    const float* b1 = (const float*)d_in[11];
    const float* W2 = (const float*)d_in[12];
    const float* b2 = (const float*)d_in[13];
    const float* g2 = (const float*)d_in[14];
    const float* be2 = (const float*)d_in[15];
    const float* g3 = (const float*)d_in[16];
    const float* be3 = (const float*)d_in[17];

    // workspace map (peak ~124.1 MiB):
    //  [0,32M)    videoBF -> OUTbf -> XBF
    //  [32M,64M)  K bf16  -> (Ybuf lower half) -> H bf16 (quarter)
    //  [64M,96M)  V bf16  -> (Ybuf upper half) -> F bf16
    //  [32M,96M)  Ybuf fp32 (after attention)
    //  [96M,120M) bf16 weights: Wq,Wk,Wv,Wo (2MB ea), W1 (8MB), W2 (8MB)
    //  [120M,124M) ctx fp32 | +64KB ksum | +256B kmax
    char* ws = (char*)d_ws;
    const size_t MB = 1048576ull;
    ushort_t* videoBF = (ushort_t*)(ws + 0);
    ushort_t* Kbuf = (ushort_t*)(ws + 32 * MB);
    ushort_t* Vbuf = (ushort_t*)(ws + 64 * MB);
    ushort_t* WqBF = (ushort_t*)(ws + 96 * MB);
    ushort_t* WkBF = (ushort_t*)(ws + 98 * MB);
    ushort_t* WvBF = (ushort_t*)(ws + 100 * MB);
    ushort_t* WoBF = (ushort_t*)(ws + 102 * MB);
    ushort_t* W1BF = (ushort_t*)(ws + 104 * MB);
    ushort_t* W2BF = (ushort_t*)(ws + 112 * MB);
    float* ctxbuf = (float*)(ws + 120 * MB);
    float* ksum   = (float*)(ws + 124 * MB);
    unsigned* kmax = (unsigned*)(ws + 124 * MB + 65536);
    ushort_t* OUTbf = (ushort_t*)(ws + 0);
    ushort_t* XBF   = (ushort_t*)(ws + 0);
    float* Ybuf = (float*)(ws + 32 * MB);
    ushort_t* Hbuf = (ushort_t*)(ws + 32 * MB);
    ushort_t* Fbf  = (ushort_t*)(ws + 64 * MB);
    float* Qbuf = (float*)d_out;   // Q, then X(post-LN1), then final out
    float* Xbuf = (float*)d_out;

    dim3 blk(256);

    // fp32 -> bf16 conversions
    cvt_bf16<<<dim3(ROWS * DMODEL / 1024), blk, 0, stream>>>(video, videoBF, ROWS * DMODEL / 4);
    cvt_bf16<<<dim3(DMODEL * DMODEL / 1024), blk, 0, stream>>>(Wq, WqBF, DMODEL * DMODEL / 4);
    cvt_bf16<<<dim3(DMODEL * DMODEL / 1024), blk, 0, stream>>>(Wk, WkBF, DMODEL * DMODEL / 4);
    cvt_bf16<<<dim3(DMODEL * DMODEL / 1024), blk, 0, stream>>>(Wv, WvBF, DMODEL * DMODEL / 4);
    cvt_bf16<<<dim3(DMODEL * DMODEL / 1024), blk, 0, stream>>>(Wo, WoBF, DMODEL * DMODEL / 4);
    cvt_bf16<<<dim3(DFF * DMODEL / 1024), blk, 0, stream>>>(W1, W1BF, DFF * DMODEL / 4);
    cvt_bf16<<<dim3(DFF * DMODEL / 1024), blk, 0, stream>>>(W2, W2BF, DFF * DMODEL / 4);

    // QKV projections (bf16 MFMA)
    dim3 gQKV(DMODEL / 128, ROWS / 128);   // (8,128)
    gemm_mfma<4, float><<<gQKV, blk, 0, stream>>>(videoBF, WqBF, bq, Qbuf, DMODEL, DMODEL, 0);
    gemm_mfma<4, ushort_t><<<gQKV, blk, 0, stream>>>(videoBF, WkBF, bk, Kbuf, DMODEL, DMODEL, 0);
    gemm_mfma<4, ushort_t><<<gQKV, blk, 0, stream>>>(videoBF, WvBF, bv, Vbuf, DMODEL, DMODEL, 0);

    hipMemsetAsync(ws + 120 * MB, 0, 4 * MB + 65536 + 256, stream);  // ctx=0, ksum=0, kmax=-inf

    kstab_kernel<<<dim3(N_TOK / 128, BHN), blk, 0, stream>>>(Kbuf, proj, kmax);
    ctxkp_kernel<<<dim3(MFEAT / 64, BHN, 8), blk, 0, stream>>>(Kbuf, Vbuf, proj, kmax, ctxbuf, ksum);
    qout_kernel<<<dim3(N_TOK / 16, BHN), blk, 0, stream>>>(Qbuf, proj, ctxbuf, ksum, OUTbf);

    gemm_mfma<4, float><<<gQKV, blk, 0, stream>>>(OUTbf, WoBF, bo, Ybuf, DMODEL, DMODEL, 0);
    ln_kernel<<<dim3(ROWS), blk, 0, stream>>>(video, Ybuf, 0, g2, be2, Xbuf, XBF);

    // FFN in four 4096-row quarters; H bf16 reuses [32M,64M), FF2 out bf16 at [64M,96M)
    for (int q = 0; q < 4; ++q) {
        const size_t r0 = (size_t)q * 4096;
        gemm_mfma<4, ushort_t><<<dim3(DFF / 128, 4096 / 128), blk, 0, stream>>>(
            XBF + r0 * DMODEL, W1BF, b1, Hbuf, DFF, DMODEL, 1);
        gemm_mfma<2, ushort_t><<<dim3(DMODEL / 64, 4096 / 128), blk, 0, stream>>>(
            Hbuf, W2BF, b2, Fbf + r0 * DMODEL, DMODEL, DFF, 0);
    }
    ln_kernel<<<dim3(ROWS), blk, 0, stream>>>(Xbuf, Fbf, 1, g3, be3, (float*)d_out, nullptr);
}

// Round 5
// 2388.686 us; speedup vs baseline: 3.7656x; 1.3595x over previous
//
#include <hip/hip_runtime.h>
#include <hip/hip_bf16.h>

// PerformerSelfLayer: B=4, N=4096, D=1024, H=16, DH=64, M=256, DFF=4096
#define N_TOK   4096
#define DMODEL  1024
#define NHEADS  16
#define DH      64
#define MFEAT   256
#define DFF     4096
#define BATCH   4
#define ROWS    (BATCH * N_TOK)   // 16384
#define BHN     (BATCH * NHEADS)  // 64

#define NORMF      0.35355339059327373f  // 64^-0.25
#define HALF_NORM2 0.0625f               // 0.5 * norm^2
#define RATIO      0.0625f               // 256^-0.5
#define EPSK       1e-4f
#define LNEPS      1e-5f

typedef unsigned short ushort_t;
using bfrag = __attribute__((ext_vector_type(8))) short;   // 8 bf16 (4 VGPRs)
using facc  = __attribute__((ext_vector_type(4))) float;   // 4 fp32 acc

__device__ __forceinline__ float b2f(ushort_t u) {
    return __bfloat162float(__builtin_bit_cast(__hip_bfloat16, u));
}
__device__ __forceinline__ ushort_t f2b(float f) {
    return __builtin_bit_cast(ushort_t, __float2bfloat16(f));
}
__device__ __forceinline__ void stC(float* p, float v) { *p = v; }
__device__ __forceinline__ void stC(ushort_t* p, float v) { *p = f2b(v); }

// order-preserving float->uint key for atomicMax; memset(0) is below any real key
__device__ __forceinline__ unsigned fkey(float f) {
    unsigned u = __float_as_uint(f);
    return (u & 0x80000000u) ? ~u : (u | 0x80000000u);
}
__device__ __forceinline__ float fdec(unsigned k) {
    return (k & 0x80000000u) ? __uint_as_float(k ^ 0x80000000u) : __uint_as_float(~k);
}

// ---------------- fp32 -> bf16 conversion (vectorized)
__global__ __launch_bounds__(256) void cvt_bf16(const float* __restrict__ s,
                                                ushort_t* __restrict__ d, int n4) {
    int i = blockIdx.x * 256 + threadIdx.x;
    if (i >= n4) return;
    float4 v = ((const float4*)s)[i];
    ushort_t o0 = f2b(v.x), o1 = f2b(v.y), o2 = f2b(v.z), o3 = f2b(v.w);
    ((ushort4*)d)[i] = make_ushort4(o0, o1, o2, o3);
}

// ---------------- bf16 MFMA GEMM: C[M,N] = A[M,K] (bf16) * W[N,K]^T (bf16) + bias
template <int FJ, typename OT>
__global__ __launch_bounds__(256) void gemm_mfma(
    const ushort_t* __restrict__ A, const ushort_t* __restrict__ W,
    const float* __restrict__ bias, OT* __restrict__ C,
    int Nout, int K, int relu)
{
    constexpr int BN = FJ * 32;
    __shared__ short As[128][40];
    __shared__ short Ws[BN][40];
    const int t = threadIdx.x;
    const int m0 = blockIdx.y * 128, n0 = blockIdx.x * BN;
    const int lane = t & 63, wave = t >> 6;
    const int wr = (wave >> 1) * 64, wc = (wave & 1) * (FJ * 16);
    const int lm = lane & 15, kq = (lane >> 4) * 8;
    facc acc[4][FJ];
#pragma unroll
    for (int i = 0; i < 4; ++i)
#pragma unroll
        for (int j = 0; j < FJ; ++j) acc[i][j] = (facc){0.f, 0.f, 0.f, 0.f};

    for (int k0 = 0; k0 < K; k0 += 32) {
#pragma unroll
        for (int it = 0; it < 2; ++it) {
            int ch = t + it * 256;
            int row = ch >> 2, c8 = (ch & 3) * 8;
            *(uint4*)&As[row][c8] = *(const uint4*)(A + (size_t)(m0 + row) * K + k0 + c8);
        }
#pragma unroll
        for (int it = 0; it < BN / 64; ++it) {
            int ch = t + it * 256;
            int row = ch >> 2, c8 = (ch & 3) * 8;
            *(uint4*)&Ws[row][c8] = *(const uint4*)(W + (size_t)(n0 + row) * K + k0 + c8);
        }
        __syncthreads();
        bfrag af[4], bf[FJ];
#pragma unroll
        for (int i = 0; i < 4; ++i) af[i] = *(bfrag*)&As[wr + i * 16 + lm][kq];
#pragma unroll
        for (int j = 0; j < FJ; ++j) bf[j] = *(bfrag*)&Ws[wc + j * 16 + lm][kq];
#pragma unroll
        for (int i = 0; i < 4; ++i)
#pragma unroll
            for (int j = 0; j < FJ; ++j)
                acc[i][j] = __builtin_amdgcn_mfma_f32_16x16x32_bf16(af[i], bf[j], acc[i][j], 0, 0, 0);
        __syncthreads();
    }
    const int rq = (lane >> 4) * 4;
#pragma unroll
    for (int i = 0; i < 4; ++i)
#pragma unroll
        for (int j = 0; j < FJ; ++j) {
            int col = n0 + wc + j * 16 + lm;
            float bc = bias[col];
#pragma unroll
            for (int r = 0; r < 4; ++r) {
                int row = m0 + wr + i * 16 + rq + r;
                float v = acc[i][j][r] + bc;
                if (relu) v = fmaxf(v, 0.f);
                stC(C + (size_t)row * Nout + col, v);
            }
        }
}

// ---------------- per-(b,h) global max of norm*(k . proj^T); K is bf16
__global__ __launch_bounds__(256) void kstab_kernel(
    const ushort_t* __restrict__ Kmat, const float* __restrict__ proj,
    unsigned* __restrict__ kmax)
{
    __shared__ float pl[MFEAT][65];
    __shared__ float krow[DH];
    __shared__ float red[256];
    const int t = threadIdx.x;
    for (int idx = t; idx < MFEAT * DH; idx += 256)
        pl[idx >> 6][idx & 63] = proj[idx];
    const int bh = blockIdx.y, b = bh >> 4, h = bh & 15;
    const int n0 = blockIdx.x * 128;
    const ushort_t* Kb = Kmat + ((size_t)b * N_TOK) * DMODEL + h * DH;
    float mx = -1e30f;
    __syncthreads();
    for (int r = 0; r < 128; ++r) {
        if (t < DH) krow[t] = b2f(Kb[(size_t)(n0 + r) * DMODEL + t]);
        __syncthreads();
        float dot = 0.f;
#pragma unroll
        for (int j = 0; j < DH; ++j) dot += krow[j] * pl[t][j];
        mx = fmaxf(mx, dot);
        __syncthreads();
    }
    red[t] = mx;
    __syncthreads();
    for (int s = 128; s > 0; s >>= 1) {
        if (t < s) red[t] = fmaxf(red[t], red[t + s]);
        __syncthreads();
    }
    if (t == 0) atomicMax(kmax + bh, fkey(red[0] * NORMF));
}

// ---------------- fused kp + ctx + ksum, N split 8 ways, atomic accumulate
__global__ __launch_bounds__(256) void ctxkp_kernel(
    const ushort_t* __restrict__ Kmat, const ushort_t* __restrict__ V,
    const float* __restrict__ proj, const unsigned* __restrict__ kmax,
    float* __restrict__ ctx, float* __restrict__ ksum)
{
    __shared__ float P[64][65];
    __shared__ float Ks[16][65];
    __shared__ float Vs[16][65];
    __shared__ float KPs[16][65];
    __shared__ float diag[16];
    __shared__ float ksred[256];
    const int t = threadIdx.x;
    const int bh = blockIdx.y, b = bh >> 4, h = bh & 15;
    const int m0 = blockIdx.x * 64;
    const int nbase = blockIdx.z * (N_TOK / 8);
    for (int idx = t; idx < 64 * DH; idx += 256)
        P[idx >> 6][idx & 63] = proj[(size_t)(m0 + (idx >> 6)) * DH + (idx & 63)];
    const float stab = fdec(kmax[bh]);
    const ushort_t* Kb = Kmat + ((size_t)b * N_TOK) * DMODEL + h * DH;
    const ushort_t* Vb = V + ((size_t)b * N_TOK) * DMODEL + h * DH;
    const int mm = t & 63, rq = t >> 6;
    const int tm = t >> 4, tn = t & 15;
    float acc[4][4] = {{0.f, 0.f, 0.f, 0.f}};
    float ksacc = 0.f;
    __syncthreads();
    for (int n0 = nbase; n0 < nbase + N_TOK / 8; n0 += 16) {
#pragma unroll
        for (int i = 0; i < 4; ++i) {
            int idx = t + i * 256;
            int r = idx >> 6, c = idx & 63;
            Ks[r][c] = b2f(Kb[(size_t)(n0 + r) * DMODEL + c]);
            Vs[r][c] = b2f(Vb[(size_t)(n0 + r) * DMODEL + c]);
        }
        __syncthreads();
        if (t < 16) {
            float s = 0.f;
#pragma unroll
            for (int j = 0; j < DH; ++j) s += Ks[t][j] * Ks[t][j];
            diag[t] = s;
        }
        __syncthreads();
#pragma unroll
        for (int i = 0; i < 4; ++i) {
            int r = rq * 4 + i;
            float dot = 0.f;
#pragma unroll
            for (int j = 0; j < DH; ++j) dot += Ks[r][j] * P[mm][j];
            float val = RATIO * (expf(NORMF * dot - HALF_NORM2 * diag[r] - stab) + EPSK);
            KPs[r][mm] = val;
            ksacc += val;
        }
        __syncthreads();
#pragma unroll
        for (int r = 0; r < 16; ++r) {
            float av[4], bv[4];
#pragma unroll
            for (int i = 0; i < 4; ++i) av[i] = KPs[r][tm * 4 + i];
#pragma unroll
            for (int j = 0; j < 4; ++j) bv[j] = Vs[r][tn * 4 + j];
#pragma unroll
            for (int i = 0; i < 4; ++i)
#pragma unroll
                for (int j = 0; j < 4; ++j) acc[i][j] = fmaf(av[i], bv[j], acc[i][j]);
        }
        __syncthreads();
    }
    ksred[t] = ksacc;
    __syncthreads();
    if (t < 64)
        atomicAdd(&ksum[bh * MFEAT + m0 + t],
                  ksred[t] + ksred[t + 64] + ksred[t + 128] + ksred[t + 192]);
    float* cb = ctx + (size_t)bh * MFEAT * DH;
#pragma unroll
    for (int i = 0; i < 4; ++i)
#pragma unroll
        for (int j = 0; j < 4; ++j)
            atomicAdd(&cb[(size_t)(m0 + tm * 4 + i) * DH + tn * 4 + j], acc[i][j]);
}

// ---------------- ctx [bh][256][64] fp32 -> ctxT [bh][64][256] bf16 (LDS tile transpose)
__global__ __launch_bounds__(256) void ctx_transpose(
    const float* __restrict__ ctx, ushort_t* __restrict__ ctxT)
{
    __shared__ float tile[64][65];
    const int bh = blockIdx.x, t = threadIdx.x;
    const float* cb = ctx + (size_t)bh * MFEAT * DH;
    ushort_t* ob = ctxT + (size_t)bh * DH * MFEAT;
    for (int mb = 0; mb < 4; ++mb) {
#pragma unroll
        for (int i = 0; i < 16; ++i) {
            int idx = t + i * 256;           // 4096 elems: m-local = idx>>6, d = idx&63
            tile[idx >> 6][idx & 63] = cb[(size_t)(mb * 64 + (idx >> 6)) * DH + (idx & 63)];
        }
        __syncthreads();
#pragma unroll
        for (int i = 0; i < 16; ++i) {
            int idx = t + i * 256;           // d = idx>>6, m-local = idx&63
            ob[(size_t)(idx >> 6) * MFEAT + mb * 64 + (idx & 63)] = f2b(tile[idx & 63][idx >> 6]);
        }
        __syncthreads();
    }
}

// ---------------- XP[h][n][m] = NORMF * (Q[b,n,h*64:] . proj[m,:]) — bf16 MFMA, K=64
__global__ __launch_bounds__(256) void xp_gemm(
    const float* __restrict__ Q,            // + b*N_TOK*DMODEL
    const ushort_t* __restrict__ projBF,    // [256][64]
    ushort_t* __restrict__ XP)              // [16][4096][256] (per batch)
{
    __shared__ short As[128][40];   // n-rows x k
    __shared__ short Ws[128][40];   // m-rows x k
    const int t = threadIdx.x;
    const int m0 = blockIdx.x * 128, n0v = blockIdx.y * 128, h = blockIdx.z;
    const float* Qb = Q + h * DH;
    const int lane = t & 63, wave = t >> 6;
    const int wr = (wave >> 1) * 64, wc = (wave & 1) * 64;
    const int lm = lane & 15, kq = (lane >> 4) * 8;
    facc acc[4][4];
#pragma unroll
    for (int i = 0; i < 4; ++i)
#pragma unroll
        for (int j = 0; j < 4; ++j) acc[i][j] = (facc){0.f, 0.f, 0.f, 0.f};

    for (int k0 = 0; k0 < 64; k0 += 32) {
#pragma unroll
        for (int it = 0; it < 4; ++it) {       // A: 128x32 fp32 -> bf16 (1024 float4 chunks)
            int ch = t + it * 256;
            int row = ch >> 3, c4 = (ch & 7) * 4;
            float4 v = *(const float4*)(Qb + (size_t)(n0v + row) * DMODEL + k0 + c4);
            As[row][c4 + 0] = (short)f2b(v.x);
            As[row][c4 + 1] = (short)f2b(v.y);
            As[row][c4 + 2] = (short)f2b(v.z);
            As[row][c4 + 3] = (short)f2b(v.w);
        }
#pragma unroll
        for (int it = 0; it < 2; ++it) {       // W: 128x32 bf16
            int ch = t + it * 256;
            int row = ch >> 2, c8 = (ch & 3) * 8;
            *(uint4*)&Ws[row][c8] = *(const uint4*)(projBF + (size_t)(m0 + row) * DH + k0 + c8);
        }
        __syncthreads();
        bfrag af[4], bf[4];
#pragma unroll
        for (int i = 0; i < 4; ++i) af[i] = *(bfrag*)&As[wr + i * 16 + lm][kq];
#pragma unroll
        for (int j = 0; j < 4; ++j) bf[j] = *(bfrag*)&Ws[wc + j * 16 + lm][kq];
#pragma unroll
        for (int i = 0; i < 4; ++i)
#pragma unroll
            for (int j = 0; j < 4; ++j)
                acc[i][j] = __builtin_amdgcn_mfma_f32_16x16x32_bf16(af[i], bf[j], acc[i][j], 0, 0, 0);
        __syncthreads();
    }
    const int rq = (lane >> 4) * 4;
    ushort_t* xb = XP + (size_t)h * N_TOK * MFEAT;
#pragma unroll
    for (int i = 0; i < 4; ++i)
#pragma unroll
        for (int j = 0; j < 4; ++j) {
            int col = m0 + wc + j * 16 + lm;
#pragma unroll
            for (int r = 0; r < 4; ++r) {
                int row = n0v + wr + i * 16 + rq + r;
                xb[(size_t)row * MFEAT + col] = f2b(NORMF * acc[i][j][r]);
            }
        }
}

// ---------------- per-row: stab/exp/EPSK -> QP bf16 in-place + denom (wave-per-row, no barriers)
__global__ __launch_bounds__(256) void qp_kernel(
    ushort_t* __restrict__ XP,              // [16][4096][256] in/out
    const float* __restrict__ Q,            // + b*N_TOK*DMODEL
    const float* __restrict__ ksum,         // + b*16*256
    float* __restrict__ denom)              // [65536] per batch
{
    const int lane = threadIdx.x & 63, wave = threadIdx.x >> 6;
    const int row0 = (blockIdx.x * 4 + wave) * 8;
    for (int rr = 0; rr < 8; ++rr) {
        const int row = row0 + rr;               // h = row>>12, n = row&4095
        const int h = row >> 12, n = row & 4095;
        ushort_t* xr = XP + (size_t)row * MFEAT + lane * 4;
        ushort4 xv = *(ushort4*)xr;
        float x0 = b2f(xv.x), x1 = b2f(xv.y), x2 = b2f(xv.z), x3 = b2f(xv.w);
        float qv = Q[(size_t)n * DMODEL + h * DH + lane];
        float ss = qv * qv;
#pragma unroll
        for (int o = 32; o >= 1; o >>= 1) ss += __shfl_xor(ss, o);
        float mx = fmaxf(fmaxf(x0, x1), fmaxf(x2, x3));
#pragma unroll
        for (int o = 32; o >= 1; o >>= 1) mx = fmaxf(mx, __shfl_xor(mx, o));
        const float sh = HALF_NORM2 * ss + mx;
        float p0 = RATIO * (expf(x0 - sh) + EPSK);
        float p1 = RATIO * (expf(x1 - sh) + EPSK);
        float p2 = RATIO * (expf(x2 - sh) + EPSK);
        float p3 = RATIO * (expf(x3 - sh) + EPSK);
        ushort4 pv = make_ushort4(f2b(p0), f2b(p1), f2b(p2), f2b(p3));
        *(ushort4*)xr = pv;
        float4 ks4 = *(const float4*)(ksum + h * MFEAT + lane * 4);
        float dn = b2f(pv.x) * ks4.x + b2f(pv.y) * ks4.y + b2f(pv.z) * ks4.z + b2f(pv.w) * ks4.w;
#pragma unroll
        for (int o = 32; o >= 1; o >>= 1) dn += __shfl_xor(dn, o);
        if (lane == 0) denom[row] = dn;
    }
}

// ---------------- OUT[n][h*64+d] = (QP . ctxT[d]) / denom — bf16 MFMA, K=256
__global__ __launch_bounds__(256) void out_gemm(
    const ushort_t* __restrict__ XP,        // QP [16][4096][256] (per batch)
    const ushort_t* __restrict__ ctxT,      // + b*16*64*256: [h][64][256]
    const float* __restrict__ denom,        // [65536] per batch
    ushort_t* __restrict__ OUT)             // + b*N_TOK*DMODEL
{
    __shared__ short As[128][40];   // QP rows x k
    __shared__ short Ws[64][40];    // ctxT rows (=out cols) x k
    const int t = threadIdx.x;
    const int n0 = blockIdx.x * 128, h = blockIdx.y;
    const ushort_t* A = XP + (size_t)h * N_TOK * MFEAT;
    const ushort_t* W = ctxT + (size_t)h * DH * MFEAT;
    const float* dnb = denom + (size_t)h * N_TOK;
    ushort_t* ob = OUT + h * DH;
    const int lane = t & 63, wave = t >> 6;
    const int wr = (wave >> 1) * 64, wc = (wave & 1) * 32;
    const int lm = lane & 15, kq = (lane >> 4) * 8;
    facc acc[4][2];
#pragma unroll
    for (int i = 0; i < 4; ++i)
#pragma unroll
        for (int j = 0; j < 2; ++j) acc[i][j] = (facc){0.f, 0.f, 0.f, 0.f};

    for (int k0 = 0; k0 < MFEAT; k0 += 32) {
#pragma unroll
        for (int it = 0; it < 2; ++it) {       // A: 128x32
            int ch = t + it * 256;
            int row = ch >> 2, c8 = (ch & 3) * 8;
            *(uint4*)&As[row][c8] = *(const uint4*)(A + (size_t)(n0 + row) * MFEAT + k0 + c8);
        }
        {                                       // W: 64x32
            int row = t >> 2, c8 = (t & 3) * 8;
            *(uint4*)&Ws[row][c8] = *(const uint4*)(W + (size_t)row * MFEAT + k0 + c8);
        }
        __syncthreads();
        bfrag af[4], bf[2];
#pragma unroll
        for (int i = 0; i < 4; ++i) af[i] = *(bfrag*)&As[wr + i * 16 + lm][kq];
#pragma unroll
        for (int j = 0; j < 2; ++j) bf[j] = *(bfrag*)&Ws[wc + j * 16 + lm][kq];
#pragma unroll
        for (int i = 0; i < 4; ++i)
#pragma unroll
            for (int j = 0; j < 2; ++j)
                acc[i][j] = __builtin_amdgcn_mfma_f32_16x16x32_bf16(af[i], bf[j], acc[i][j], 0, 0, 0);
        __syncthreads();
    }
    const int rq = (lane >> 4) * 4;
#pragma unroll
    for (int i = 0; i < 4; ++i)
#pragma unroll
        for (int r = 0; r < 4; ++r) {
            int row = n0 + wr + i * 16 + rq + r;
            float inv = 1.f / dnb[row];
#pragma unroll
            for (int j = 0; j < 2; ++j) {
                int col = wc + j * 16 + lm;
                ob[(size_t)row * DMODEL + col] = f2b(acc[i][j][r] * inv);
            }
        }
}

// ---------------- LayerNorm: out = LN(A + Badd)*g + b; optional bf16 copy of out
__global__ __launch_bounds__(256) void ln_kernel(
    const float* __restrict__ A, const void* __restrict__ Badd, int badd_bf16,
    const float* __restrict__ g, const float* __restrict__ bb,
    float* __restrict__ out, ushort_t* __restrict__ out_bf)
{
    __shared__ float red[256];
    const int row = blockIdx.x, t = threadIdx.x;
    const float* a = A + (size_t)row * DMODEL;
    float v[4];
    float s = 0.f;
#pragma unroll
    for (int i = 0; i < 4; ++i) {
        int col = t + i * 256;
        float add = badd_bf16 ? b2f(((const ushort_t*)Badd)[(size_t)row * DMODEL + col])
                              : ((const float*)Badd)[(size_t)row * DMODEL + col];
        v[i] = a[col] + add;
        s += v[i];
    }
    red[t] = s;
    __syncthreads();
    for (int st = 128; st > 0; st >>= 1) { if (t < st) red[t] += red[t + st]; __syncthreads(); }
    float mu = red[0] * (1.f / DMODEL);
    __syncthreads();
    float sq = 0.f;
#pragma unroll
    for (int i = 0; i < 4; ++i) { float dlt = v[i] - mu; sq += dlt * dlt; }
    red[t] = sq;
    __syncthreads();
    for (int st = 128; st > 0; st >>= 1) { if (t < st) red[t] += red[t + st]; __syncthreads(); }
    float rstd = rsqrtf(red[0] * (1.f / DMODEL) + LNEPS);
    float* o = out + (size_t)row * DMODEL;
#pragma unroll
    for (int i = 0; i < 4; ++i) {
        int col = t + i * 256;
        float val = (v[i] - mu) * rstd * g[col] + bb[col];
        o[col] = val;
        if (out_bf) out_bf[(size_t)row * DMODEL + col] = f2b(val);
    }
}

extern "C" void kernel_launch(void* const* d_in, const int* in_sizes, int n_in,
                              void* d_out, int out_size, void* d_ws, size_t ws_size,
                              hipStream_t stream)
{
    const float* video = (const float*)d_in[0];
    const float* Wq = (const float*)d_in[1];
    const float* bq = (const float*)d_in[2];
    const float* Wk = (const float*)d_in[3];
    const float* bk = (const float*)d_in[4];
    const float* Wv = (const float*)d_in[5];
    const float* bv = (const float*)d_in[6];
    const float* Wo = (const float*)d_in[7];
    const float* bo = (const float*)d_in[8];
    const float* proj = (const float*)d_in[9];
    const float* W1 = (const float*)d_in[10];
    const float* b1 = (const float*)d_in[11];
    const float* W2 = (const float*)d_in[12];
    const float* b2 = (const float*)d_in[13];
    const float* g2 = (const float*)d_in[14];
    const float* be2 = (const float*)d_in[15];
    const float* g3 = (const float*)d_in[16];
    const float* be3 = (const float*)d_in[17];

    // workspace map (peak ~124.1 MiB):
    //  [0,32M)    videoBF -> OUTbf -> XBF
    //  [32M,64M)  K bf16 ; after ctxkp: XP/QP bf16 (per-batch, 33.55MB -> reaches 65.6M)
    //  [64M,96M)  V bf16 ; after ctxkp: XP tail | ctxT@88M (2MB) | projBF@90M | denom@92M
    //  [32M,96M)  Ybuf fp32 (after out_gemm done)
    //  [96M,120M) bf16 weights: Wq,Wk,Wv,Wo (2MB ea), W1 (8MB), W2 (8MB)
    //  [120M,124M) ctx fp32 | +64KB ksum | +256B kmax
    char* ws = (char*)d_ws;
    const size_t MB = 1048576ull;
    ushort_t* videoBF = (ushort_t*)(ws + 0);
    ushort_t* Kbuf = (ushort_t*)(ws + 32 * MB);
    ushort_t* Vbuf = (ushort_t*)(ws + 64 * MB);
    ushort_t* WqBF = (ushort_t*)(ws + 96 * MB);
    ushort_t* WkBF = (ushort_t*)(ws + 98 * MB);
    ushort_t* WvBF = (ushort_t*)(ws + 100 * MB);
    ushort_t* WoBF = (ushort_t*)(ws + 102 * MB);
    ushort_t* W1BF = (ushort_t*)(ws + 104 * MB);
    ushort_t* W2BF = (ushort_t*)(ws + 112 * MB);
    float* ctxbuf = (float*)(ws + 120 * MB);
    float* ksum   = (float*)(ws + 124 * MB);
    unsigned* kmax = (unsigned*)(ws + 124 * MB + 65536);
    ushort_t* XPbuf  = (ushort_t*)(ws + 32 * MB);    // per-batch QP features
    ushort_t* ctxTbf = (ushort_t*)(ws + 88 * MB);    // [64][64][256] bf16
    ushort_t* projBF = (ushort_t*)(ws + 90 * MB);    // [256][64] bf16
    float* denomB    = (float*)(ws + 92 * MB);       // [65536] per batch
    ushort_t* OUTbf = (ushort_t*)(ws + 0);
    ushort_t* XBF   = (ushort_t*)(ws + 0);
    float* Ybuf = (float*)(ws + 32 * MB);
    ushort_t* Hbuf = (ushort_t*)(ws + 32 * MB);
    ushort_t* Fbf  = (ushort_t*)(ws + 64 * MB);
    float* Qbuf = (float*)d_out;   // Q fp32, then X(post-LN1), then final out
    float* Xbuf = (float*)d_out;

    dim3 blk(256);

    // fp32 -> bf16 conversions
    cvt_bf16<<<dim3(ROWS * DMODEL / 1024), blk, 0, stream>>>(video, videoBF, ROWS * DMODEL / 4);
    cvt_bf16<<<dim3(DMODEL * DMODEL / 1024), blk, 0, stream>>>(Wq, WqBF, DMODEL * DMODEL / 4);
    cvt_bf16<<<dim3(DMODEL * DMODEL / 1024), blk, 0, stream>>>(Wk, WkBF, DMODEL * DMODEL / 4);
    cvt_bf16<<<dim3(DMODEL * DMODEL / 1024), blk, 0, stream>>>(Wv, WvBF, DMODEL * DMODEL / 4);
    cvt_bf16<<<dim3(DMODEL * DMODEL / 1024), blk, 0, stream>>>(Wo, WoBF, DMODEL * DMODEL / 4);
    cvt_bf16<<<dim3(DFF * DMODEL / 1024), blk, 0, stream>>>(W1, W1BF, DFF * DMODEL / 4);
    cvt_bf16<<<dim3(DFF * DMODEL / 1024), blk, 0, stream>>>(W2, W2BF, DFF * DMODEL / 4);

    // QKV projections (bf16 MFMA)
    dim3 gQKV(DMODEL / 128, ROWS / 128);   // (8,128)
    gemm_mfma<4, float><<<gQKV, blk, 0, stream>>>(videoBF, WqBF, bq, Qbuf, DMODEL, DMODEL, 0);
    gemm_mfma<4, ushort_t><<<gQKV, blk, 0, stream>>>(videoBF, WkBF, bk, Kbuf, DMODEL, DMODEL, 0);
    gemm_mfma<4, ushort_t><<<gQKV, blk, 0, stream>>>(videoBF, WvBF, bv, Vbuf, DMODEL, DMODEL, 0);

    hipMemsetAsync(ws + 120 * MB, 0, 4 * MB + 65536 + 256, stream);  // ctx=0, ksum=0, kmax=-inf

    kstab_kernel<<<dim3(N_TOK / 128, BHN), blk, 0, stream>>>(Kbuf, proj, kmax);
    ctxkp_kernel<<<dim3(MFEAT / 64, BHN, 8), blk, 0, stream>>>(Kbuf, Vbuf, proj, kmax, ctxbuf, ksum);

    // Q-side attention: GEMM-ified (K,V regions now dead)
    ctx_transpose<<<dim3(BHN), blk, 0, stream>>>(ctxbuf, ctxTbf);
    cvt_bf16<<<dim3(16), blk, 0, stream>>>(proj, projBF, MFEAT * DH / 4);
    for (int b = 0; b < BATCH; ++b) {
        const float* Qb = Qbuf + (size_t)b * N_TOK * DMODEL;
        xp_gemm<<<dim3(MFEAT / 128, N_TOK / 128, NHEADS), blk, 0, stream>>>(Qb, projBF, XPbuf);
        qp_kernel<<<dim3(NHEADS * N_TOK / 32), blk, 0, stream>>>(
            XPbuf, Qb, ksum + (size_t)b * NHEADS * MFEAT, denomB);
        out_gemm<<<dim3(N_TOK / 128, NHEADS), blk, 0, stream>>>(
            XPbuf, ctxTbf + (size_t)b * NHEADS * DH * MFEAT, denomB,
            OUTbf + (size_t)b * N_TOK * DMODEL);
    }

    gemm_mfma<4, float><<<gQKV, blk, 0, stream>>>(OUTbf, WoBF, bo, Ybuf, DMODEL, DMODEL, 0);
    ln_kernel<<<dim3(ROWS), blk, 0, stream>>>(video, Ybuf, 0, g2, be2, Xbuf, XBF);

    // FFN in four 4096-row quarters; H bf16 reuses [32M,64M), FF2 out bf16 at [64M,96M)
    for (int q = 0; q < 4; ++q) {
        const size_t r0 = (size_t)q * 4096;
        gemm_mfma<4, ushort_t><<<dim3(DFF / 128, 4096 / 128), blk, 0, stream>>>(
            XBF + r0 * DMODEL, W1BF, b1, Hbuf, DFF, DMODEL, 1);
        gemm_mfma<2, ushort_t><<<dim3(DMODEL / 64, 4096 / 128), blk, 0, stream>>>(
            Hbuf, W2BF, b2, Fbf + r0 * DMODEL, DMODEL, DFF, 0);
    }
    ln_kernel<<<dim3(ROWS), blk, 0, stream>>>(Xbuf, Fbf, 1, g3, be3, (float*)d_out, nullptr);
}

// Round 6
// 1838.547 us; speedup vs baseline: 4.8924x; 1.2992x over previous
//
#include <hip/hip_runtime.h>
#include <hip/hip_bf16.h>

// PerformerSelfLayer: B=4, N=4096, D=1024, H=16, DH=64, M=256, DFF=4096
#define N_TOK   4096
#define DMODEL  1024
#define NHEADS  16
#define DH      64
#define MFEAT   256
#define DFF     4096
#define BATCH   4
#define ROWS    (BATCH * N_TOK)   // 16384

#define NORMF      0.35355339059327373f  // 64^-0.25
#define HALF_NORM2 0.0625f               // 0.5 * norm^2
#define RATIO      0.0625f               // 256^-0.5
#define EPSK       1e-4f
#define LNEPS      1e-5f

typedef unsigned short ushort_t;
using bfrag = __attribute__((ext_vector_type(8))) short;   // 8 bf16 (4 VGPRs)
using facc  = __attribute__((ext_vector_type(4))) float;   // 4 fp32 acc
using ush8  = __attribute__((ext_vector_type(8))) unsigned short;

__device__ __forceinline__ float b2f(ushort_t u) {
    return __bfloat162float(__builtin_bit_cast(__hip_bfloat16, u));
}
__device__ __forceinline__ ushort_t f2b(float f) {
    return __builtin_bit_cast(ushort_t, __float2bfloat16(f));
}
__device__ __forceinline__ void stC(float* p, float v) { *p = v; }
__device__ __forceinline__ void stC(ushort_t* p, float v) { *p = f2b(v); }

// order-preserving float->uint key for atomicMax; memset(0) is below any real key
__device__ __forceinline__ unsigned fkey(float f) {
    unsigned u = __float_as_uint(f);
    return (u & 0x80000000u) ? ~u : (u | 0x80000000u);
}
__device__ __forceinline__ float fdec(unsigned k) {
    return (k & 0x80000000u) ? __uint_as_float(k ^ 0x80000000u) : __uint_as_float(~k);
}

// ---------------- fp32 -> bf16 conversion (vectorized)
__global__ __launch_bounds__(256) void cvt_bf16(const float* __restrict__ s,
                                                ushort_t* __restrict__ d, int n4) {
    int i = blockIdx.x * 256 + threadIdx.x;
    if (i >= n4) return;
    float4 v = ((const float4*)s)[i];
    ((ushort4*)d)[i] = make_ushort4(f2b(v.x), f2b(v.y), f2b(v.z), f2b(v.w));
}

// ---------------- bf16 MFMA GEMM: C[M,N] = A[M,K] (bf16) * W[N,K]^T (bf16) + bias
template <int FJ, typename OT>
__global__ __launch_bounds__(256) void gemm_mfma(
    const ushort_t* __restrict__ A, const ushort_t* __restrict__ W,
    const float* __restrict__ bias, OT* __restrict__ C,
    int Nout, int K, int relu)
{
    constexpr int BN = FJ * 32;
    __shared__ short As[128][40];
    __shared__ short Ws[BN][40];
    const int t = threadIdx.x;
    const int m0 = blockIdx.y * 128, n0 = blockIdx.x * BN;
    const int lane = t & 63, wave = t >> 6;
    const int wr = (wave >> 1) * 64, wc = (wave & 1) * (FJ * 16);
    const int lm = lane & 15, kq = (lane >> 4) * 8;
    facc acc[4][FJ];
#pragma unroll
    for (int i = 0; i < 4; ++i)
#pragma unroll
        for (int j = 0; j < FJ; ++j) acc[i][j] = (facc){0.f, 0.f, 0.f, 0.f};

    for (int k0 = 0; k0 < K; k0 += 32) {
#pragma unroll
        for (int it = 0; it < 2; ++it) {
            int ch = t + it * 256;
            int row = ch >> 2, c8 = (ch & 3) * 8;
            *(uint4*)&As[row][c8] = *(const uint4*)(A + (size_t)(m0 + row) * K + k0 + c8);
        }
#pragma unroll
        for (int it = 0; it < BN / 64; ++it) {
            int ch = t + it * 256;
            int row = ch >> 2, c8 = (ch & 3) * 8;
            *(uint4*)&Ws[row][c8] = *(const uint4*)(W + (size_t)(n0 + row) * K + k0 + c8);
        }
        __syncthreads();
        bfrag af[4], bf[FJ];
#pragma unroll
        for (int i = 0; i < 4; ++i) af[i] = *(bfrag*)&As[wr + i * 16 + lm][kq];
#pragma unroll
        for (int j = 0; j < FJ; ++j) bf[j] = *(bfrag*)&Ws[wc + j * 16 + lm][kq];
#pragma unroll
        for (int i = 0; i < 4; ++i)
#pragma unroll
            for (int j = 0; j < FJ; ++j)
                acc[i][j] = __builtin_amdgcn_mfma_f32_16x16x32_bf16(af[i], bf[j], acc[i][j], 0, 0, 0);
        __syncthreads();
    }
    const int rq = (lane >> 4) * 4;
#pragma unroll
    for (int i = 0; i < 4; ++i)
#pragma unroll
        for (int j = 0; j < FJ; ++j) {
            int col = n0 + wc + j * 16 + lm;
            float bc = bias[col];
#pragma unroll
            for (int r = 0; r < 4; ++r) {
                int row = m0 + wr + i * 16 + rq + r;
                float v = acc[i][j][r] + bc;
                if (relu) v = fmaxf(v, 0.f);
                stC(C + (size_t)row * Nout + col, v);
            }
        }
}

// ---------------- V_b [4096][1024] -> VT [16][64][4096] (per-head transpose)
__global__ __launch_bounds__(256) void vt_kernel(
    const ushort_t* __restrict__ V, ushort_t* __restrict__ VT)
{
    __shared__ ushort_t tile[64][68];
    const int t = threadIdx.x;
    const int n0 = blockIdx.x * 64, h = blockIdx.y;
#pragma unroll
    for (int i = 0; i < 4; ++i) {
        int idx = t + i * 256;                    // 1024 ushort4 chunks
        int nl = idx >> 4, d4 = (idx & 15) * 4;
        ushort4 v = *(const ushort4*)(V + (size_t)(n0 + nl) * DMODEL + h * DH + d4);
        tile[nl][d4 + 0] = v.x; tile[nl][d4 + 1] = v.y;
        tile[nl][d4 + 2] = v.z; tile[nl][d4 + 3] = v.w;
    }
    __syncthreads();
#pragma unroll
    for (int i = 0; i < 4; ++i) {
        int idx = t + i * 256;
        int d = idx >> 4, n4 = (idx & 15) * 4;
        ushort4 o = make_ushort4(tile[n4][d], tile[n4 + 1][d], tile[n4 + 2][d], tile[n4 + 3][d]);
        *(ushort4*)(VT + (size_t)h * DH * N_TOK + (size_t)d * N_TOK + n0 + n4) = o;
    }
}

// ---------------- diagK[h][n] = sum_dh K[n][h*64+dh]^2  (wave per n, shuffle)
__global__ __launch_bounds__(256) void diagk_kernel(
    const ushort_t* __restrict__ Kb, float* __restrict__ diagK)
{
    const int lane = threadIdx.x & 63, wave = threadIdx.x >> 6;
    const int n = blockIdx.x * 4 + wave;
    const ushort_t* kr = Kb + (size_t)n * DMODEL + lane * 16;
    ush8 a = *(const ush8*)kr;
    ush8 b = *(const ush8*)(kr + 8);
    float s = 0.f;
#pragma unroll
    for (int e = 0; e < 8; ++e) { float x = b2f(a[e]); s += x * x; }
#pragma unroll
    for (int e = 0; e < 8; ++e) { float x = b2f(b[e]); s += x * x; }
    s += __shfl_xor(s, 1);
    s += __shfl_xor(s, 2);
    if ((lane & 3) == 0) diagK[(size_t)(lane >> 2) * N_TOK + n] = s;
}

// ---------------- K-side feature GEMM: acc = proj[m,:] . K[n, h*64:] (K=64, MFMA)
// mode 0: per-h global max -> atomicMax kmax16.  mode 1: exp epilogue -> KP[h][m][n] bf16
__global__ __launch_bounds__(256) void xk_kernel(
    const ushort_t* __restrict__ projBF,   // [256][64]
    const ushort_t* __restrict__ Kb,       // [4096][1024]
    const float* __restrict__ diagK,       // [16][4096]
    unsigned* __restrict__ kmax16,         // [16]
    ushort_t* __restrict__ KP,             // [16][256][4096]
    int mode)
{
    __shared__ short As[128][40];
    __shared__ short Ws[128][40];
    const int t = threadIdx.x;
    const int m0 = blockIdx.x * 128, n0 = blockIdx.y * 128, h = blockIdx.z;
    const ushort_t* Kh = Kb + h * DH;
    const int lane = t & 63, wave = t >> 6;
    const int wr = (wave >> 1) * 64, wc = (wave & 1) * 64;
    const int lm = lane & 15, kq = (lane >> 4) * 8;
    facc acc[4][4];
#pragma unroll
    for (int i = 0; i < 4; ++i)
#pragma unroll
        for (int j = 0; j < 4; ++j) acc[i][j] = (facc){0.f, 0.f, 0.f, 0.f};

    for (int k0 = 0; k0 < DH; k0 += 32) {
#pragma unroll
        for (int it = 0; it < 2; ++it) {
            int ch = t + it * 256;
            int row = ch >> 2, c8 = (ch & 3) * 8;
            *(uint4*)&As[row][c8] = *(const uint4*)(projBF + (size_t)(m0 + row) * DH + k0 + c8);
            *(uint4*)&Ws[row][c8] = *(const uint4*)(Kh + (size_t)(n0 + row) * DMODEL + k0 + c8);
        }
        __syncthreads();
        bfrag af[4], bf[4];
#pragma unroll
        for (int i = 0; i < 4; ++i) af[i] = *(bfrag*)&As[wr + i * 16 + lm][kq];
#pragma unroll
        for (int j = 0; j < 4; ++j) bf[j] = *(bfrag*)&Ws[wc + j * 16 + lm][kq];
#pragma unroll
        for (int i = 0; i < 4; ++i)
#pragma unroll
            for (int j = 0; j < 4; ++j)
                acc[i][j] = __builtin_amdgcn_mfma_f32_16x16x32_bf16(af[i], bf[j], acc[i][j], 0, 0, 0);
        __syncthreads();
    }
    const int rq = (lane >> 4) * 4;
    if (mode == 0) {
        float mx = -1e30f;
#pragma unroll
        for (int i = 0; i < 4; ++i)
#pragma unroll
            for (int j = 0; j < 4; ++j)
#pragma unroll
                for (int r = 0; r < 4; ++r) mx = fmaxf(mx, acc[i][j][r]);
        mx *= NORMF;
#pragma unroll
        for (int o = 32; o >= 1; o >>= 1) mx = fmaxf(mx, __shfl_xor(mx, o));
        if (lane == 0) atomicMax(kmax16 + h, fkey(mx));
    } else {
        const float stab = fdec(kmax16[h]);
        ushort_t* kb = KP + (size_t)h * MFEAT * N_TOK;
#pragma unroll
        for (int j = 0; j < 4; ++j) {
            int n = n0 + wc + j * 16 + lm;
            float dg = HALF_NORM2 * diagK[(size_t)h * N_TOK + n] + stab;
#pragma unroll
            for (int i = 0; i < 4; ++i)
#pragma unroll
                for (int r = 0; r < 4; ++r) {
                    int m = m0 + wr + i * 16 + rq + r;
                    float x = NORMF * acc[i][j][r];
                    kb[(size_t)m * N_TOK + n] = f2b(RATIO * (expf(x - dg) + EPSK));
                }
        }
    }
}

// ---------------- ksum[h*256+m] = sum_n KP[h][m][n]  (wave per row)
__global__ __launch_bounds__(256) void ksum_kernel(
    const ushort_t* __restrict__ KP, float* __restrict__ ksum)
{
    const int lane = threadIdx.x & 63, wave = threadIdx.x >> 6;
    const int row = blockIdx.x * 4 + wave;
    const ushort_t* kr = KP + (size_t)row * N_TOK;
    float s = 0.f;
#pragma unroll
    for (int it = 0; it < 8; ++it) {
        ush8 v = *(const ush8*)(kr + it * 512 + lane * 8);
#pragma unroll
        for (int e = 0; e < 8; ++e) s += b2f(v[e]);
    }
#pragma unroll
    for (int o = 32; o >= 1; o >>= 1) s += __shfl_xor(s, o);
    if (lane == 0) ksum[row] = s;
}

// ---------------- ctx[h][m][d] += sum_{n in chunk} KP[h][m][n] * VT[h][d][n]  (MFMA)
__global__ __launch_bounds__(256) void ctx_mfma(
    const ushort_t* __restrict__ KP, const ushort_t* __restrict__ VT,
    float* __restrict__ ctx)
{
    __shared__ short As[128][40];
    __shared__ short Vs[64][40];
    const int t = threadIdx.x;
    const int z = blockIdx.x, mh = blockIdx.y, h = blockIdx.z;
    const ushort_t* A = KP + (size_t)h * MFEAT * N_TOK + (size_t)mh * 128 * N_TOK;
    const ushort_t* W = VT + (size_t)h * DH * N_TOK;
    const int lane = t & 63, wave = t >> 6;
    const int wr = (wave >> 1) * 64, wc = (wave & 1) * 32;
    const int lm = lane & 15, kq = (lane >> 4) * 8;
    facc acc[4][2];
#pragma unroll
    for (int i = 0; i < 4; ++i)
#pragma unroll
        for (int j = 0; j < 2; ++j) acc[i][j] = (facc){0.f, 0.f, 0.f, 0.f};

    const int kbeg = z * 512, kend = kbeg + 512;
    for (int k0 = kbeg; k0 < kend; k0 += 32) {
#pragma unroll
        for (int it = 0; it < 2; ++it) {
            int ch = t + it * 256;
            int row = ch >> 2, c8 = (ch & 3) * 8;
            *(uint4*)&As[row][c8] = *(const uint4*)(A + (size_t)row * N_TOK + k0 + c8);
        }
        {
            int row = t >> 2, c8 = (t & 3) * 8;
            *(uint4*)&Vs[row][c8] = *(const uint4*)(W + (size_t)row * N_TOK + k0 + c8);
        }
        __syncthreads();
        bfrag af[4], bf[2];
#pragma unroll
        for (int i = 0; i < 4; ++i) af[i] = *(bfrag*)&As[wr + i * 16 + lm][kq];
#pragma unroll
        for (int j = 0; j < 2; ++j) bf[j] = *(bfrag*)&Vs[wc + j * 16 + lm][kq];
#pragma unroll
        for (int i = 0; i < 4; ++i)
#pragma unroll
            for (int j = 0; j < 2; ++j)
                acc[i][j] = __builtin_amdgcn_mfma_f32_16x16x32_bf16(af[i], bf[j], acc[i][j], 0, 0, 0);
        __syncthreads();
    }
    const int rq = (lane >> 4) * 4;
    float* cb = ctx + (size_t)h * MFEAT * DH + (size_t)mh * 128 * DH;
#pragma unroll
    for (int i = 0; i < 4; ++i)
#pragma unroll
        for (int j = 0; j < 2; ++j)
#pragma unroll
            for (int r = 0; r < 4; ++r) {
                int m = wr + i * 16 + rq + r;
                int d = wc + j * 16 + lm;
                atomicAdd(cb + (size_t)m * DH + d, acc[i][j][r]);
            }
}

// ---------------- ctx [h][256][64] fp32 -> ctxT [h][64][256] bf16
__global__ __launch_bounds__(256) void ctx_transpose(
    const float* __restrict__ ctx, ushort_t* __restrict__ ctxT)
{
    __shared__ float tile[64][65];
    const int bh = blockIdx.x, t = threadIdx.x;
    const float* cb = ctx + (size_t)bh * MFEAT * DH;
    ushort_t* ob = ctxT + (size_t)bh * DH * MFEAT;
    for (int mb = 0; mb < 4; ++mb) {
#pragma unroll
        for (int i = 0; i < 16; ++i) {
            int idx = t + i * 256;
            tile[idx >> 6][idx & 63] = cb[(size_t)(mb * 64 + (idx >> 6)) * DH + (idx & 63)];
        }
        __syncthreads();
#pragma unroll
        for (int i = 0; i < 16; ++i) {
            int idx = t + i * 256;
            ob[(size_t)(idx >> 6) * MFEAT + mb * 64 + (idx & 63)] = f2b(tile[idx & 63][idx >> 6]);
        }
        __syncthreads();
    }
}

// ---------------- XP[h][n][m] = NORMF * (Q[n,h*64:] . proj[m,:]) — MFMA, K=64
__global__ __launch_bounds__(256) void xp_gemm(
    const float* __restrict__ Q, const ushort_t* __restrict__ projBF,
    ushort_t* __restrict__ XP)
{
    __shared__ short As[128][40];
    __shared__ short Ws[128][40];
    const int t = threadIdx.x;
    const int m0 = blockIdx.x * 128, n0v = blockIdx.y * 128, h = blockIdx.z;
    const float* Qb = Q + h * DH;
    const int lane = t & 63, wave = t >> 6;
    const int wr = (wave >> 1) * 64, wc = (wave & 1) * 64;
    const int lm = lane & 15, kq = (lane >> 4) * 8;
    facc acc[4][4];
#pragma unroll
    for (int i = 0; i < 4; ++i)
#pragma unroll
        for (int j = 0; j < 4; ++j) acc[i][j] = (facc){0.f, 0.f, 0.f, 0.f};

    for (int k0 = 0; k0 < 64; k0 += 32) {
#pragma unroll
        for (int it = 0; it < 4; ++it) {
            int ch = t + it * 256;
            int row = ch >> 3, c4 = (ch & 7) * 4;
            float4 v = *(const float4*)(Qb + (size_t)(n0v + row) * DMODEL + k0 + c4);
            As[row][c4 + 0] = (short)f2b(v.x);
            As[row][c4 + 1] = (short)f2b(v.y);
            As[row][c4 + 2] = (short)f2b(v.z);
            As[row][c4 + 3] = (short)f2b(v.w);
        }
#pragma unroll
        for (int it = 0; it < 2; ++it) {
            int ch = t + it * 256;
            int row = ch >> 2, c8 = (ch & 3) * 8;
            *(uint4*)&Ws[row][c8] = *(const uint4*)(projBF + (size_t)(m0 + row) * DH + k0 + c8);
        }
        __syncthreads();
        bfrag af[4], bf[4];
#pragma unroll
        for (int i = 0; i < 4; ++i) af[i] = *(bfrag*)&As[wr + i * 16 + lm][kq];
#pragma unroll
        for (int j = 0; j < 4; ++j) bf[j] = *(bfrag*)&Ws[wc + j * 16 + lm][kq];
#pragma unroll
        for (int i = 0; i < 4; ++i)
#pragma unroll
            for (int j = 0; j < 4; ++j)
                acc[i][j] = __builtin_amdgcn_mfma_f32_16x16x32_bf16(af[i], bf[j], acc[i][j], 0, 0, 0);
        __syncthreads();
    }
    const int rq = (lane >> 4) * 4;
    ushort_t* xb = XP + (size_t)h * N_TOK * MFEAT;
#pragma unroll
    for (int i = 0; i < 4; ++i)
#pragma unroll
        for (int j = 0; j < 4; ++j) {
            int col = m0 + wc + j * 16 + lm;
#pragma unroll
            for (int r = 0; r < 4; ++r) {
                int row = n0v + wr + i * 16 + rq + r;
                xb[(size_t)row * MFEAT + col] = f2b(NORMF * acc[i][j][r]);
            }
        }
}

// ---------------- per-row q-features: stab/exp -> QP bf16 in-place + denom
__global__ __launch_bounds__(256) void qp_kernel(
    ushort_t* __restrict__ XP, const float* __restrict__ Q,
    const float* __restrict__ ksum, float* __restrict__ denom)
{
    const int lane = threadIdx.x & 63, wave = threadIdx.x >> 6;
    const int row0 = (blockIdx.x * 4 + wave) * 8;
    for (int rr = 0; rr < 8; ++rr) {
        const int row = row0 + rr;
        const int h = row >> 12, n = row & 4095;
        ushort_t* xr = XP + (size_t)row * MFEAT + lane * 4;
        ushort4 xv = *(ushort4*)xr;
        float x0 = b2f(xv.x), x1 = b2f(xv.y), x2 = b2f(xv.z), x3 = b2f(xv.w);
        float qv = Q[(size_t)n * DMODEL + h * DH + lane];
        float ss = qv * qv;
#pragma unroll
        for (int o = 32; o >= 1; o >>= 1) ss += __shfl_xor(ss, o);
        float mx = fmaxf(fmaxf(x0, x1), fmaxf(x2, x3));
#pragma unroll
        for (int o = 32; o >= 1; o >>= 1) mx = fmaxf(mx, __shfl_xor(mx, o));
        const float sh = HALF_NORM2 * ss + mx;
        float p0 = RATIO * (expf(x0 - sh) + EPSK);
        float p1 = RATIO * (expf(x1 - sh) + EPSK);
        float p2 = RATIO * (expf(x2 - sh) + EPSK);
        float p3 = RATIO * (expf(x3 - sh) + EPSK);
        ushort4 pv = make_ushort4(f2b(p0), f2b(p1), f2b(p2), f2b(p3));
        *(ushort4*)xr = pv;
        float4 ks4 = *(const float4*)(ksum + h * MFEAT + lane * 4);
        float dn = b2f(pv.x) * ks4.x + b2f(pv.y) * ks4.y + b2f(pv.z) * ks4.z + b2f(pv.w) * ks4.w;
#pragma unroll
        for (int o = 32; o >= 1; o >>= 1) dn += __shfl_xor(dn, o);
        if (lane == 0) denom[row] = dn;
    }
}

// ---------------- OUT[n][h*64+d] = (QP . ctxT[d]) / denom — MFMA, K=256
__global__ __launch_bounds__(256) void out_gemm(
    const ushort_t* __restrict__ XP, const ushort_t* __restrict__ ctxT,
    const float* __restrict__ denom, ushort_t* __restrict__ OUT)
{
    __shared__ short As[128][40];
    __shared__ short Ws[64][40];
    const int t = threadIdx.x;
    const int n0 = blockIdx.x * 128, h = blockIdx.y;
    const ushort_t* A = XP + (size_t)h * N_TOK * MFEAT;
    const ushort_t* W = ctxT + (size_t)h * DH * MFEAT;
    const float* dnb = denom + (size_t)h * N_TOK;
    ushort_t* ob = OUT + h * DH;
    const int lane = t & 63, wave = t >> 6;
    const int wr = (wave >> 1) * 64, wc = (wave & 1) * 32;
    const int lm = lane & 15, kq = (lane >> 4) * 8;
    facc acc[4][2];
#pragma unroll
    for (int i = 0; i < 4; ++i)
#pragma unroll
        for (int j = 0; j < 2; ++j) acc[i][j] = (facc){0.f, 0.f, 0.f, 0.f};

    for (int k0 = 0; k0 < MFEAT; k0 += 32) {
#pragma unroll
        for (int it = 0; it < 2; ++it) {
            int ch = t + it * 256;
            int row = ch >> 2, c8 = (ch & 3) * 8;
            *(uint4*)&As[row][c8] = *(const uint4*)(A + (size_t)(n0 + row) * MFEAT + k0 + c8);
        }
        {
            int row = t >> 2, c8 = (t & 3) * 8;
            *(uint4*)&Ws[row][c8] = *(const uint4*)(W + (size_t)row * MFEAT + k0 + c8);
        }
        __syncthreads();
        bfrag af[4], bf[2];
#pragma unroll
        for (int i = 0; i < 4; ++i) af[i] = *(bfrag*)&As[wr + i * 16 + lm][kq];
#pragma unroll
        for (int j = 0; j < 2; ++j) bf[j] = *(bfrag*)&Ws[wc + j * 16 + lm][kq];
#pragma unroll
        for (int i = 0; i < 4; ++i)
#pragma unroll
            for (int j = 0; j < 2; ++j)
                acc[i][j] = __builtin_amdgcn_mfma_f32_16x16x32_bf16(af[i], bf[j], acc[i][j], 0, 0, 0);
        __syncthreads();
    }
    const int rq = (lane >> 4) * 4;
#pragma unroll
    for (int i = 0; i < 4; ++i)
#pragma unroll
        for (int r = 0; r < 4; ++r) {
            int row = n0 + wr + i * 16 + rq + r;
            float inv = 1.f / dnb[row];
#pragma unroll
            for (int j = 0; j < 2; ++j) {
                int col = wc + j * 16 + lm;
                ob[(size_t)row * DMODEL + col] = f2b(acc[i][j][r] * inv);
            }
        }
}

// ---------------- LayerNorm: out = LN(A + Badd)*g + b; optional bf16 copy
__global__ __launch_bounds__(256) void ln_kernel(
    const float* __restrict__ A, const void* __restrict__ Badd, int badd_bf16,
    const float* __restrict__ g, const float* __restrict__ bb,
    float* __restrict__ out, ushort_t* __restrict__ out_bf)
{
    __shared__ float red[256];
    const int row = blockIdx.x, t = threadIdx.x;
    const float* a = A + (size_t)row * DMODEL;
    float v[4];
    float s = 0.f;
#pragma unroll
    for (int i = 0; i < 4; ++i) {
        int col = t + i * 256;
        float add = badd_bf16 ? b2f(((const ushort_t*)Badd)[(size_t)row * DMODEL + col])
                              : ((const float*)Badd)[(size_t)row * DMODEL + col];
        v[i] = a[col] + add;
        s += v[i];
    }
    red[t] = s;
    __syncthreads();
    for (int st = 128; st > 0; st >>= 1) { if (t < st) red[t] += red[t + st]; __syncthreads(); }
    float mu = red[0] * (1.f / DMODEL);
    __syncthreads();
    float sq = 0.f;
#pragma unroll
    for (int i = 0; i < 4; ++i) { float dlt = v[i] - mu; sq += dlt * dlt; }
    red[t] = sq;
    __syncthreads();
    for (int st = 128; st > 0; st >>= 1) { if (t < st) red[t] += red[t + st]; __syncthreads(); }
    float rstd = rsqrtf(red[0] * (1.f / DMODEL) + LNEPS);
    float* o = out + (size_t)row * DMODEL;
#pragma unroll
    for (int i = 0; i < 4; ++i) {
        int col = t + i * 256;
        float val = (v[i] - mu) * rstd * g[col] + bb[col];
        o[col] = val;
        if (out_bf) out_bf[(size_t)row * DMODEL + col] = f2b(val);
    }
}

extern "C" void kernel_launch(void* const* d_in, const int* in_sizes, int n_in,
                              void* d_out, int out_size, void* d_ws, size_t ws_size,
                              hipStream_t stream)
{
    const float* video = (const float*)d_in[0];
    const float* Wq = (const float*)d_in[1];
    const float* bq = (const float*)d_in[2];
    const float* Wk = (const float*)d_in[3];
    const float* bk = (const float*)d_in[4];
    const float* Wv = (const float*)d_in[5];
    const float* bv = (const float*)d_in[6];
    const float* Wo = (const float*)d_in[7];
    const float* bo = (const float*)d_in[8];
    const float* proj = (const float*)d_in[9];
    const float* W1 = (const float*)d_in[10];
    const float* b1 = (const float*)d_in[11];
    const float* W2 = (const float*)d_in[12];
    const float* b2 = (const float*)d_in[13];
    const float* g2 = (const float*)d_in[14];
    const float* be2 = (const float*)d_in[15];
    const float* g3 = (const float*)d_in[16];
    const float* be3 = (const float*)d_in[17];

    // workspace map (peak ~124 MiB), per-batch pipeline with aliasing:
    //  [0,32M)      videoBF (alive whole loop)
    //  [32M,40M)    K_b bf16        -> XBF_b (after xk passes)
    //  [40M,48M)    V_b bf16        -> F_b (FF2 out)
    //  [48M,56M)    VT_b bf16       -> Y_b (attn@Wo out)
    //  [56M,89.5M)  KP (33.5M)      -> XP (q-side) -> H_b (FFN hidden, 32M)
    //  [89.5M,90.5M) ctx_b fp32 | [90.5,91M) ctxT_b bf16
    //  [91M,92M)    smalls: diagK, ksum, denom, kmax16, projBF
    //  [92M,100M)   OUT_b bf16
    //  [100M,124M)  weights bf16: Wq,Wk,Wv,Wo (2M ea), W1 (8M), W2 (8M)
    //  d_out: Q fp32 (all batches) -> X_b fp32 -> final out
    char* ws = (char*)d_ws;
    const size_t MB = 1048576ull;
    ushort_t* videoBF = (ushort_t*)(ws + 0);
    ushort_t* Kb   = (ushort_t*)(ws + 32 * MB);
    ushort_t* XBFb = (ushort_t*)(ws + 32 * MB);
    ushort_t* Vb   = (ushort_t*)(ws + 40 * MB);
    ushort_t* Fb   = (ushort_t*)(ws + 40 * MB);
    ushort_t* VTb  = (ushort_t*)(ws + 48 * MB);
    ushort_t* Yb   = (ushort_t*)(ws + 48 * MB);
    ushort_t* KP   = (ushort_t*)(ws + 56 * MB);   // also XP, then H_b
    ushort_t* Hb   = (ushort_t*)(ws + 56 * MB);
    float*    ctxb = (float*)(ws + 93847552ull);            // 89.5 MB
    ushort_t* ctxTb = (ushort_t*)(ws + 93847552ull + MB);   // 90.5 MB
    char* smalls = ws + 91 * MB + 393216ull;                // 91.375 MB
    float*    diagK  = (float*)(smalls);                    // 256 KB
    float*    ksum   = (float*)(smalls + 262144);           // 16 KB
    float*    denomB = (float*)(smalls + 278528);           // 256 KB
    unsigned* kmax16 = (unsigned*)(smalls + 540672);        // 64 B
    ushort_t* projBF = (ushort_t*)(smalls + 541184);        // 32 KB
    ushort_t* OUTb = (ushort_t*)(ws + 92 * MB);
    ushort_t* WqBF = (ushort_t*)(ws + 100 * MB);
    ushort_t* WkBF = (ushort_t*)(ws + 102 * MB);
    ushort_t* WvBF = (ushort_t*)(ws + 104 * MB);
    ushort_t* WoBF = (ushort_t*)(ws + 106 * MB);
    ushort_t* W1BF = (ushort_t*)(ws + 108 * MB);
    ushort_t* W2BF = (ushort_t*)(ws + 116 * MB);
    float* Qbuf = (float*)d_out;

    dim3 blk(256);

    // one-time fp32 -> bf16 conversions
    cvt_bf16<<<dim3(ROWS * DMODEL / 1024), blk, 0, stream>>>(video, videoBF, ROWS * DMODEL / 4);
    cvt_bf16<<<dim3(DMODEL * DMODEL / 1024), blk, 0, stream>>>(Wq, WqBF, DMODEL * DMODEL / 4);
    cvt_bf16<<<dim3(DMODEL * DMODEL / 1024), blk, 0, stream>>>(Wk, WkBF, DMODEL * DMODEL / 4);
    cvt_bf16<<<dim3(DMODEL * DMODEL / 1024), blk, 0, stream>>>(Wv, WvBF, DMODEL * DMODEL / 4);
    cvt_bf16<<<dim3(DMODEL * DMODEL / 1024), blk, 0, stream>>>(Wo, WoBF, DMODEL * DMODEL / 4);
    cvt_bf16<<<dim3(DFF * DMODEL / 1024), blk, 0, stream>>>(W1, W1BF, DFF * DMODEL / 4);
    cvt_bf16<<<dim3(DFF * DMODEL / 1024), blk, 0, stream>>>(W2, W2BF, DFF * DMODEL / 4);
    cvt_bf16<<<dim3(16), blk, 0, stream>>>(proj, projBF, MFEAT * DH / 4);

    // Q projection, all rows (fp32 out into d_out)
    gemm_mfma<4, float><<<dim3(8, ROWS / 128), blk, 0, stream>>>(
        videoBF, WqBF, bq, Qbuf, DMODEL, DMODEL, 0);

    dim3 gP(8, 32);   // per-batch 4096-row projection grid

    for (int b = 0; b < BATCH; ++b) {
        const size_t roff = (size_t)b * N_TOK;
        const ushort_t* vbf = videoBF + roff * DMODEL;
        float* Qb = Qbuf + roff * DMODEL;

        // K/V projections (per batch)
        gemm_mfma<4, ushort_t><<<gP, blk, 0, stream>>>(vbf, WkBF, bk, Kb, DMODEL, DMODEL, 0);
        gemm_mfma<4, ushort_t><<<gP, blk, 0, stream>>>(vbf, WvBF, bv, Vb, DMODEL, DMODEL, 0);
        vt_kernel<<<dim3(64, 16), blk, 0, stream>>>(Vb, VTb);
        diagk_kernel<<<dim3(1024), blk, 0, stream>>>(Kb, diagK);

        hipMemsetAsync(ctxb, 0, MB, stream);
        hipMemsetAsync(kmax16, 0, 64, stream);

        // K-side features: max pass, then exp pass -> KP[h][m][n]
        xk_kernel<<<dim3(2, 32, 16), blk, 0, stream>>>(projBF, Kb, diagK, kmax16, KP, 0);
        xk_kernel<<<dim3(2, 32, 16), blk, 0, stream>>>(projBF, Kb, diagK, kmax16, KP, 1);
        ksum_kernel<<<dim3(1024), blk, 0, stream>>>(KP, ksum);
        ctx_mfma<<<dim3(8, 2, 16), blk, 0, stream>>>(KP, VTb, ctxb);
        ctx_transpose<<<dim3(16), blk, 0, stream>>>(ctxb, ctxTb);

        // Q-side (XP reuses the KP region)
        xp_gemm<<<dim3(2, 32, 16), blk, 0, stream>>>(Qb, projBF, KP);
        qp_kernel<<<dim3(2048), blk, 0, stream>>>(KP, Qb, ksum, denomB);
        out_gemm<<<dim3(32, 16), blk, 0, stream>>>(KP, ctxTb, denomB, OUTb);

        // Wo, LN1, FFN, LN2 (all per batch)
        gemm_mfma<4, ushort_t><<<gP, blk, 0, stream>>>(OUTb, WoBF, bo, Yb, DMODEL, DMODEL, 0);
        ln_kernel<<<dim3(N_TOK), blk, 0, stream>>>(
            video + roff * DMODEL, Yb, 1, g2, be2, Qb, XBFb);
        gemm_mfma<4, ushort_t><<<dim3(32, 32), blk, 0, stream>>>(
            XBFb, W1BF, b1, Hb, DFF, DMODEL, 1);
        gemm_mfma<2, ushort_t><<<dim3(16, 32), blk, 0, stream>>>(
            Hb, W2BF, b2, Fb, DMODEL, DFF, 0);
        ln_kernel<<<dim3(N_TOK), blk, 0, stream>>>(
            Qb, Fb, 1, g3, be3, Qb, nullptr);
    }
}